// Round 10
// baseline (229.929 us; speedup 1.0000x reference)
//
#include <hip/hip_runtime.h>
#include <hip/hip_bf16.h>

typedef __hip_bfloat16 bf16;
typedef float f32x4 __attribute__((ext_vector_type(4)));
typedef short s16x8 __attribute__((ext_vector_type(8)));

#define B_    8
#define LP    12
#define NC    4096
#define NO    128
#define NAPO  8
#define NN    4224
#define E_    64
#define A_    64
#define H_    256
#define QC    80
#define PROJ0 65
#define NCHUNK 17

#define TOT_IN 688896
#define QTF_C  67584     // 132*512 shorts per (b,c) group
#define QTF_B  337920    // 5*QTF_C per batch
#define TB_P   983040    // dwords per kh-partial: 96*4*2560

struct Ptr16 { const void* p[16]; };
union U8 { s16x8 v; unsigned u[4]; };

__device__ __forceinline__ float b2f(bf16 x){ return __bfloat162float(x); }
__device__ __forceinline__ float bs2f(unsigned short s){
  union { unsigned u; float f; } x; x.u = ((unsigned)s) << 16; return x.f;
}
__device__ __forceinline__ unsigned short f2bs(float f){
  bf16 h = __float2bfloat16(f);
  union { bf16 h; unsigned short s; } x; x.h = h; return x.s;
}
__device__ __forceinline__ unsigned pack2(float a, float b){
  return (unsigned)f2bs(a) | ((unsigned)f2bs(b) << 16);
}
__device__ __forceinline__ float lo16f(unsigned w){
  union { unsigned u; float f; } x; x.u = w << 16; return x.f;
}
__device__ __forceinline__ float hi16f(unsigned w){
  union { unsigned u; float f; } x; x.u = w & 0xffff0000u; return x.f;
}
__device__ __forceinline__ float rdval(const void* p, size_t i, int fl){
  return fl ? ((const float*)p)[i] : bs2f(((const unsigned short*)p)[i]);
}

// ---------------- k_prep v3: concept tensors NOT converted (read raw downstream) ----------------
// Convert ranges: [0,65536) class/attr embeds + [589824, 688896) weights/inits. 164608 elems.
__global__ void k_prep(Ptr16 ps, int* flag, float* dst,
                       unsigned short* awFrag,
                       const int* gtc, const int* gta,
                       float* objIn, float* objOut, float* qsum_esum){
  int tid = threadIdx.x;
  // wave-local dtype detect: probe concept_embIn even half-words; fp32 garbage -> ~46% exp>=137
  const unsigned short* u = (const unsigned short*)ps.p[4];
  int hit = (((u[tid*16] >> 7) & 0xFF) >= 137) ? 1 : 0;
  unsigned long long m = __ballot(hit);
  int fl = (m != 0ULL) ? 1 : 0;
  int mb = blockIdx.x;
  if (mb < 161){
    int qi = mb*256 + tid;
    if (qi >= 41152) return;
    int idx = (qi < 16384) ? qi*4 : qi*4 + 524288;   // skip concept tensors [65536,589824)
    constexpr int cum[17] = {0,16384,32768,49152,65536,327680,589824,589888,589952,
                             622720,622976,639360,639424,672192,672448,688832,688896};
    int t = 0;
    #pragma unroll
    for (int i=1;i<16;i++) if (idx >= cum[i]) t = i;
    int off = idx - cum[t];
    float4 v;
    if (fl){
      v = *(const float4*)((const float*)ps.p[t] + off);
    } else {
      uint2 sv = *(const uint2*)((const unsigned short*)ps.p[t] + off);
      v.x = lo16f(sv.x); v.y = hi16f(sv.x);
      v.z = lo16f(sv.y); v.w = hi16f(sv.y);
    }
    *(float4*)(dst + idx) = v;
  } else if (mb < 225){
    int idx = (mb-161)*256 + tid;               // < 16384
    int j = idx & 7;
    int lane = (idx >> 3) & 63;
    int mm = (idx >> 9) & 15;
    int kc = idx >> 13;
    int e = kc*32 + (lane>>4)*8 + j;
    int h = mm*16 + (lane&15);
    awFrag[idx] = f2bs(rdval(ps.p[8], (size_t)e*H_ + h, fl));
  } else if (mb < 481){
    int idx = (mb-225)*256 + tid;               // < 65536
    int e = idx & 63; int bo = idx >> 6;
    int cls = gtc[bo];
    float vi = rdval(ps.p[0], (size_t)cls*E_ + e, fl);
    float vo = rdval(ps.p[1], (size_t)cls*E_ + e, fl);
    const int* ga = gta + bo*NAPO;
    #pragma unroll
    for (int j=0;j<NAPO;j++){
      int at = ga[j];
      vi += rdval(ps.p[2], (size_t)at*E_ + e, fl);
      vo += rdval(ps.p[3], (size_t)at*E_ + e, fl);
    }
    objIn[idx] = vi; objOut[idx] = vo;
  } else {
    if (tid < 656) qsum_esum[tid] = 0.f;        // qsum(640) + esum(16)
    if (tid == 0) *flag = fl;
  }
}

// ================ k_mid: meta(8) | QTf+qsum(136) | baseT->Aopt(80) ================
// mid_meta v3: op-skip + raw concept reads.
__device__ __forceinline__ void mid_meta(char* smem, int b, int fl, const void* coRaw,
                       const float* meta_init,
                       const float* mw1, const float* mb1, const float* mw2, const float* mb2,
                       const float* aw1, const float* ab1,
                       const int* ops, const int* args,
                       float* metaAll, float* metaH){
  unsigned* mw1p = (unsigned*)smem;               // 64*256 = 65536 B
  unsigned* mw2p = (unsigned*)(smem + 65536);     // 128*64 = 32768 B
  unsigned* aw1p = (unsigned*)(smem + 98304);     // 32*256 = 32768 B
  float* meta_s  = (float*)(smem + 131072);
  float* argx    = (float*)(smem + 131328);
  float* hid     = (float*)(smem + 131584);
  float* part    = (float*)(smem + 132608);
  int tid = threadIdx.x;

  for (int i=tid; i<64*256; i+=256){
    int j2 = i >> 8, t = i & 255;
    mw1p[i] = pack2(mw1[(2*j2)*H_ + t], mw1[(2*j2+1)*H_ + t]);
  }
  for (int i=tid; i<128*64; i+=256){
    int h2 = i >> 6, a = i & 63;
    mw2p[i] = pack2(mw2[(2*h2)*A_ + a], mw2[(2*h2+1)*A_ + a]);
  }
  for (int i=tid; i<32*256; i+=256){
    int a2 = i >> 8, t = i & 255;
    aw1p[i] = pack2(aw1[(E_+2*a2)*H_ + t], aw1[(E_+2*a2+1)*H_ + t]);
  }
  float r_mb1 = mb1[tid];
  float r_ab1 = ab1[tid];
  float r_mb2 = (tid < A_) ? mb2[tid] : 0.f;
  if (tid < A_) meta_s[tid] = meta_init[tid];
  __syncthreads();

  // initial metaH (from initial meta)
  float mh = r_ab1;
  for (int a2=0;a2<32;a2++){
    unsigned w = aw1p[a2*256 + tid];
    float2 mp = *(const float2*)&meta_s[2*a2];
    mh = fmaf(mp.x, lo16f(w), mh);
    mh = fmaf(mp.y, hi16f(w), mh);
  }

  for (int t=0;t<LP;t++){
    int op  = ops[b*LP + t];
    if (op == 0){
      int arg = args[b*LP + t];
      if (tid >= 64 && tid < 128) argx[tid-64] = rdval(coRaw, (size_t)arg*E_ + (tid-64), fl);
      __syncthreads();
      float acc = r_mb1;
      for (int j2=0;j2<32;j2++){
        unsigned w = mw1p[j2*256 + tid];
        float2 xp = *(const float2*)&meta_s[2*j2];
        acc = fmaf(xp.x, lo16f(w), acc);
        acc = fmaf(xp.y, hi16f(w), acc);
      }
      for (int j2=0;j2<32;j2++){
        unsigned w = mw1p[(32+j2)*256 + tid];
        float2 xp = *(const float2*)&argx[2*j2];
        acc = fmaf(xp.x, lo16f(w), acc);
        acc = fmaf(xp.y, hi16f(w), acc);
      }
      hid[tid] = fmaxf(acc, 0.f);
      __syncthreads();
      int wv_ = tid >> 6, l = tid & 63;
      float acc2 = 0.f;
      for (int h2 = wv_*32; h2 < wv_*32+32; h2++){
        unsigned w = mw2p[h2*64 + l];
        float2 hp = *(const float2*)&hid[2*h2];
        acc2 = fmaf(hp.x, lo16f(w), acc2);
        acc2 = fmaf(hp.y, hi16f(w), acc2);
      }
      part[wv_*64 + l] = acc2;
      __syncthreads();
      if (tid < A_){
        float s = part[tid] + part[64+tid] + part[128+tid] + part[192+tid] + r_mb2;
        meta_s[tid] = s;
      }
      __syncthreads();
      mh = r_ab1;
      for (int a2=0;a2<32;a2++){
        unsigned w = aw1p[a2*256 + tid];
        float2 mp = *(const float2*)&meta_s[2*a2];
        mh = fmaf(mp.x, lo16f(w), mh);
        mh = fmaf(mp.y, hi16f(w), mh);
      }
    }
    if (tid < A_) metaAll[(b*LP+t)*A_ + tid] = meta_s[tid];
    metaH[(b*LP+t)*H_ + tid] = mh;
  }
}

// mid_qt v3: raw concept reads + column-sum reduction (no LDS atomics) + proj-skip (op!=1 -> 0)
__device__ __forceinline__ void mid_qt(char* smem, int idx, int fl,
                       const void* ciRaw, const void* coRaw, const int* args,
                       const float* objIn, const float* objOut, const int* ops,
                       unsigned short* QTf, float* qsum){
  float* tile = (float*)smem;                  // 256*65*4 = 66560 B
  float* argv = (float*)(smem + 66560);        // 3072 B
  float* qs   = (float*)(smem + 69632);        // 320 B
  float* colp = (float*)(smem + 69952);        // 1024 B
  int b = idx / NCHUNK, chunk = idx % NCHUNK;
  int tid = threadIdx.x;
  int rows = (chunk < 16) ? 256 : 128;
  int n0 = chunk*256;
  int n = n0 + tid;
  bool valid = (tid < rows);
  if (tid < 80) qs[tid] = 0.f;
  unsigned short* Qb = QTf + (size_t)b*QTF_B + ((n>>5)*512 + (n&31));
  {
    int tot = rows*64;
    if (chunk < 16){
      for (int i=tid; i<tot; i+=256) tile[(i>>6)*65 + (i&63)] = rdval(ciRaw, (size_t)n0*E_ + i, fl);
    } else {
      const float* src = objIn + (size_t)b*NO*E_;
      for (int i=tid; i<tot; i+=256) tile[(i>>6)*65 + (i&63)] = src[i];
    }
  }
  __syncthreads();
  if (valid){
    Qb[0] = 0x3F80;
    Qb[4*QTF_C + 13*32] = 0;
    Qb[4*QTF_C + 14*32] = 0;
    Qb[4*QTF_C + 15*32] = 0;
    for (int e=0;e<64;e++){
      int qc = 1+e;
      Qb[(qc>>4)*QTF_C + (qc&15)*32] = f2bs(tile[tid*65 + e]);
    }
  }
  // column sums via row-groups (replaces 64 LDS atomics/thread)
  {
    int col = tid & 63, rg = tid >> 6;
    float s = 0.f;
    int r0 = rg*64; int r1 = r0+64; if (r1 > rows) r1 = rows;
    for (int r=r0; r<r1; r++) s += tile[r*65 + col];
    colp[rg*64 + col] = s;
  }
  __syncthreads();
  if (tid < 64) qs[1+tid] = colp[tid] + colp[64+tid] + colp[128+tid] + colp[192+tid];
  for (int i=tid;i<LP*E_;i+=256) argv[i] = rdval(coRaw, (size_t)args[b*LP + (i>>6)]*E_ + (i&63), fl);
  {
    int tot = rows*64;
    if (chunk < 16){
      for (int i=tid; i<tot; i+=256) tile[(i>>6)*65 + (i&63)] = rdval(coRaw, (size_t)n0*E_ + i, fl);
    } else {
      const float* src = objOut + (size_t)b*NO*E_;
      for (int i=tid; i<tot; i+=256) tile[(i>>6)*65 + (i&63)] = src[i];
    }
  }
  __syncthreads();
  float dots[LP];
  #pragma unroll
  for (int t=0;t<LP;t++) dots[t] = 0.f;
  for (int e=0;e<64;e++){
    float o = tile[tid*65 + e];
    #pragma unroll
    for (int t=0;t<LP;t++) dots[t] += o*argv[t*64+e];
  }
  #pragma unroll
  for (int t=0;t<LP;t++){
    int opt = ops[b*LP + t];
    float v = (valid && opt == 1) ? dots[t]*(1.f/E_) : 0.f;
    if (valid){
      int qc = PROJ0+t;
      Qb[(qc>>4)*QTF_C + (qc&15)*32] = f2bs(v);
    }
    if (opt == 1){
      float r = v;
      #pragma unroll
      for (int off=32; off>0; off>>=1) r += __shfl_down(r, off, 64);
      if ((tid & 63) == 0) atomicAdd(&qs[PROJ0+t], r);
    }
  }
  __syncthreads();
  if (tid < 80) atomicAdd(&qsum[b*QC + tid], qs[tid]);
  if (chunk == 0 && tid == 0) atomicAdd(&qsum[b*QC], (float)NN);
}

// mid_base v2: raw conceptOut reads (bf16 path loads s16x8 directly)
__device__ __forceinline__ void mid_base(int blk, int fl, const void* coRaw,
                       const float* objOut,
                       const unsigned short* awFrag,
                       unsigned short* AoptC, unsigned short* AoptO){
  int n0 = blk * 64;
  int tid = threadIdx.x;
  int w = tid >> 6, l = tid & 63, quad = l >> 4, lq = l & 15;
  int n = n0 + w*16 + lq;
  f32x4 acc[16];
  #pragma unroll
  for (int m=0;m<16;m++) acc[m] = (f32x4){0.f,0.f,0.f,0.f};
  #pragma unroll
  for (int kc=0;kc<2;kc++){
    s16x8 bfr;
    size_t eoff = (size_t)0 + kc*32 + quad*8;
    if (n < NC){
      if (fl){
        const float* src = (const float*)coRaw + (size_t)n*E_;
        #pragma unroll
        for (int j=0;j<8;j++) bfr[j] = (short)f2bs(src[eoff + j]);
      } else {
        bfr = *(const s16x8*)((const unsigned short*)coRaw + (size_t)n*E_ + eoff);
      }
    } else {
      const float* src = objOut + (size_t)(n-NC)*E_;
      #pragma unroll
      for (int j=0;j<8;j++) bfr[j] = (short)f2bs(src[eoff + j]);
    }
    const unsigned short* ap = awFrag + ((size_t)(kc*16)*64 + l)*8;
    #pragma unroll
    for (int m=0;m<16;m++){
      s16x8 af = *(const s16x8*)(ap + (size_t)m*64*8);
      acc[m] = __builtin_amdgcn_mfma_f32_16x16x32_bf16(af, bfr, acc[m], 0, 0, 0);
    }
  }
  int nl = n & 31;
  if (n < NC){
    int nch = n >> 5;
    #pragma unroll
    for (int m=0;m<16;m++){
      #pragma unroll
      for (int r=0;r<4;r++)
        AoptC[(size_t)(m*128 + nch)*512 + (quad*4+r)*32 + nl] = f2bs(acc[m][r]);
    }
  } else {
    int no = n - NC; int bb = no >> 7; int oc = (no & 127) >> 5;
    #pragma unroll
    for (int m=0;m<16;m++){
      #pragma unroll
      for (int r=0;r<4;r++)
        AoptO[(size_t)((bb*16 + m)*4 + oc)*512 + (quad*4+r)*32 + nl] = f2bs(acc[m][r]);
    }
  }
}

__global__ __launch_bounds__(256) void k_mid(
    Ptr16 ps, const int* flag,
    const float* meta_init, const float* mw1, const float* mb1, const float* mw2, const float* mb2,
    const float* aw1, const float* ab1, const int* ops, const int* args,
    const float* objIn, const float* objOut, const unsigned short* awFrag,
    float* metaAll, float* metaH, unsigned short* QTf, float* qsum,
    unsigned short* AoptC, unsigned short* AoptO){
  __shared__ __align__(16) char smem[133888];
  int fl = *flag;
  const void* ciRaw = ps.p[4];
  const void* coRaw = ps.p[5];
  int mb = blockIdx.x;
  if (mb < 8)
    mid_meta(smem, mb, fl, coRaw, meta_init, mw1, mb1, mw2, mb2, aw1, ab1, ops, args, metaAll, metaH);
  else if (mb < 144)
    mid_qt(smem, mb-8, fl, ciRaw, coRaw, args, objIn, objOut, ops, QTf, qsum);
  else
    mid_base(mb-144, fl, coRaw, objOut, awFrag, AoptC, AoptO);
}

// ---------------- k_T v7: single-wave blocks, kh 8-way K-split + op-skip ----------------
__global__ __launch_bounds__(64) void k_T(const unsigned short* AoptC, const unsigned short* AoptO,
                                          const unsigned short* QTf, const float* metaH,
                                          const int* ops, unsigned* TB){
  int bid = blockIdx.x;
  int kh = bid & 7; int ht = (bid >> 3) & 3; int bt = bid >> 5; int b = bt / LP;
  if (ops[bt] != 2) return;
  int l = threadIdx.x, quad = l >> 4, lq = l & 15;
  int off = lq*32 + quad*8;
  int start = (kh < 4) ? (kh*17) : (68 + (kh-4)*16);
  int count = (kh < 4) ? 17 : 16;
  float mh[4];
  #pragma unroll
  for (int s=0;s<4;s++) mh[s] = metaH[(size_t)bt*H_ + ht*64 + s*16 + lq];
  f32x4 acc[4][5];
  #pragma unroll
  for (int s=0;s<4;s++){
    #pragma unroll
    for (int c=0;c<5;c++) acc[s][c] = (f32x4){0.f,0.f,0.f,0.f};
  }
  const unsigned short* QTb = QTf + (size_t)b*QTF_B + off;
  const unsigned short* AC  = AoptC + (size_t)(ht*4)*65536 + off;       // 65536 = 128*512
  const unsigned short* AO  = AoptO + (size_t)(b*16 + ht*4)*2048 + off; // 2048 = 4*512
  for (int it=0; it<count; it++){
    int nchunk = start + it;
    U8 bfr[5];
    #pragma unroll
    for (int c=0;c<5;c++)
      bfr[c].v = *(const s16x8*)(QTb + (size_t)c*QTF_C + (size_t)nchunk*512);
    bool isC = (nchunk < 128);
    #pragma unroll
    for (int s=0;s<4;s++){
      U8 a;
      a.v = isC ? *(const s16x8*)(AC + (size_t)s*65536 + (size_t)nchunk*512)
                : *(const s16x8*)(AO + (size_t)s*2048 + (size_t)(nchunk-128)*512);
      float mhs = mh[s];
      U8 af;
      #pragma unroll
      for (int d=0;d<4;d++){
        unsigned wv = a.u[d];
        float lo = fmaxf(__uint_as_float(wv << 16) + mhs, 0.f);
        float hi = fmaxf(__uint_as_float(wv & 0xffff0000u) + mhs, 0.f);
        af.u[d] = __builtin_amdgcn_perm(__float_as_uint(hi), __float_as_uint(lo), 0x07060302u);
      }
      #pragma unroll
      for (int c=0;c<5;c++)
        acc[s][c] = __builtin_amdgcn_mfma_f32_16x16x32_bf16(af.v, bfr[c].v, acc[s][c], 0, 0, 0);
    }
  }
  unsigned* Tp = TB + (size_t)kh*TB_P + ((size_t)bt*4 + ht)*2560;
  #pragma unroll
  for (int s=0;s<4;s++){
    #pragma unroll
    for (int c=0;c<5;c++){
      uint2 v;
      v.x = pack2(acc[s][c][0], acc[s][c][1]);
      v.y = pack2(acc[s][c][2], acc[s][c][3]);
      *(uint2*)(Tp + (s*5+c)*128 + l*2) = v;
    }
  }
}

// ---------------- k_U v4: K-split x2 + op-skip ----------------
__global__ __launch_bounds__(256) void k_U(const unsigned* TB,
                                           const float* w2, const float* b2v,
                                           const float* qsum, const int* ops,
                                           float* Ut0, float* Ut1){
  __shared__ float Wt[128*64];
  __shared__ float Tt[128*81];
  int bid = blockIdx.x;
  int kq = bid & 1; int bt = bid >> 1; int b = bt / LP;
  if (ops[bt] != 2) return;
  int tid = threadIdx.x;
  for (int i=tid; i<8192; i+=256){
    int hl = i >> 6, e = i & 63;
    Wt[i] = w2[(kq*128 + hl)*E_ + e];
  }
  #pragma unroll
  for (int half=0; half<2; half++){
    const unsigned* base = TB + ((size_t)bt*4 + kq*2 + half)*2560;
    for (int i2=tid; i2<2560; i2+=256){
      float lo = 0.f, hi = 0.f;
      #pragma unroll
      for (int p=0;p<8;p++){
        unsigned w = base[(size_t)p*TB_P + i2];
        lo += lo16f(w); hi += hi16f(w);
      }
      int idx = 2*i2;
      int sc = idx >> 8; int ll = (idx >> 2) & 63; int r = idx & 3;
      int s = sc/5, c = sc - s*5;
      int hl = half*64 + s*16 + ((ll>>4)<<2) + r;
      int qc = c*16 + (ll&15);
      Tt[hl*81 + qc]     = lo;
      Tt[(hl+1)*81 + qc] = hi;
    }
  }
  __syncthreads();
  int el = tid & 15, ql = tid >> 4;
  float acc[4][5];
  #pragma unroll
  for (int i=0;i<4;i++){
    #pragma unroll
    for (int j=0;j<5;j++) acc[i][j]=0.f;
  }
  #pragma unroll 4
  for (int kk=0; kk<128; kk++){
    float4 wv = *(const float4*)&Wt[kk*64 + el*4];
    float ww[4] = {wv.x, wv.y, wv.z, wv.w};
    const float* tp = &Tt[kk*81 + ql*5];
    #pragma unroll
    for (int j=0;j<5;j++){
      float tv = tp[j];
      #pragma unroll
      for (int i=0;i<4;i++) acc[i][j] = fmaf(ww[i], tv, acc[i][j]);
    }
  }
  const float invN = 1.f/NN;
  float* Up = (kq ? Ut1 : Ut0) + (size_t)bt*5120;
  if (kq == 0){
    float be[4], qv[5];
    #pragma unroll
    for (int i=0;i<4;i++) be[i] = b2v[el*4+i];
    #pragma unroll
    for (int j=0;j<5;j++) qv[j] = qsum[b*QC + ql*5+j];
    #pragma unroll
    for (int i=0;i<4;i++){
      #pragma unroll
      for (int j=0;j<5;j++)
        Up[(el*4+i)*QC + ql*5+j] = (acc[i][j] + be[i]*qv[j]) * invN;
    }
  } else {
    #pragma unroll
    for (int i=0;i<4;i++){
      #pragma unroll
      for (int j=0;j<5;j++)
        Up[(el*4+i)*QC + ql*5+j] = acc[i][j] * invN;
    }
  }
}

// ---------------- k_rec v6: op-skip + gated Ul prefetch ----------------
__global__ __launch_bounds__(256) void k_rec(const float* Ut0, const float* Ut1, const float* metaAll,
                                             const int* ops, const float* att_init, float* Cm){
  __shared__ float C[QC*65];
  __shared__ float Ul[2][64*81];
  int b = blockIdx.x, tid = threadIdx.x;
  int w = tid >> 6, l = tid & 63, quad = l >> 4, lq = l & 15;
  for (int i=tid;i<QC*65;i+=256) C[i] = 0.f;
  if (tid < A_) C[tid] = att_init[tid];
  if (ops[b*LP] == 2){
    const float* U0 = Ut0 + (size_t)(b*LP)*5120;
    const float* U1 = Ut1 + (size_t)(b*LP)*5120;
    #pragma unroll
    for (int k=0;k<5;k++){
      int i = tid*4 + k*1024;
      float4 v0 = *(const float4*)&U0[i];
      float4 v1 = *(const float4*)&U1[i];
      int r = i/80, c = i%80;
      Ul[0][r*81+c]   = v0.x+v1.x; Ul[0][r*81+c+1] = v0.y+v1.y;
      Ul[0][r*81+c+2] = v0.z+v1.z; Ul[0][r*81+c+3] = v0.w+v1.w;
    }
  }
  __syncthreads();
  for (int t=0;t<LP;t++){
    int opn = (t < LP-1) ? ops[b*LP + t + 1] : 0;
    float4 rv0[5], rv1[5];
    if (opn == 2){
      const float* U0 = Ut0 + (size_t)(b*LP+t+1)*5120;
      const float* U1 = Ut1 + (size_t)(b*LP+t+1)*5120;
      #pragma unroll
      for (int k=0;k<5;k++){
        rv0[k] = *(const float4*)&U0[tid*4 + k*1024];
        rv1[k] = *(const float4*)&U1[tid*4 + k*1024];
      }
    }
    int op = ops[b*LP + t];
    f32x4 acc[4];
    if (op == 2){
      const float* Uc = Ul[t&1];
      U8 af[3][4];
      #pragma unroll
      for (int k0t=0;k0t<3;k0t++){
        #pragma unroll
        for (int s=0;s<4;s++){
          int e = s*16 + lq;
          int qb = k0t*32 + quad*8;
          float v[8];
          #pragma unroll
          for (int j=0;j<8;j++){
            int qc = qb + j;
            v[j] = (qc < QC) ? Uc[e*81 + qc] : 0.f;
          }
          #pragma unroll
          for (int d=0;d<4;d++) af[k0t][s].u[d] = pack2(v[2*d], v[2*d+1]);
        }
      }
      U8 bf[3];
      #pragma unroll
      for (int k0t=0;k0t<3;k0t++){
        int kb = k0t*32 + quad*8;
        float v[8];
        #pragma unroll
        for (int j=0;j<8;j++){
          int k = kb + j;
          v[j] = (k < QC) ? C[k*65 + w*16 + lq] : 0.f;
        }
        #pragma unroll
        for (int d=0;d<4;d++) bf[k0t].u[d] = pack2(v[2*d], v[2*d+1]);
      }
      #pragma unroll
      for (int s=0;s<4;s++){
        acc[s] = (f32x4){0.f,0.f,0.f,0.f};
        #pragma unroll
        for (int k0t=0;k0t<3;k0t++)
          acc[s] = __builtin_amdgcn_mfma_f32_16x16x32_bf16(af[k0t][s].v, bf[k0t].v, acc[s], 0, 0, 0);
      }
    }
    __syncthreads();
    if (op == 2){
      #pragma unroll
      for (int s=0;s<4;s++){
        #pragma unroll
        for (int r=0;r<4;r++){
          int e = s*16 + quad*4 + r;
          C[(1+e)*65 + w*16 + lq] += acc[s][r];
        }
      }
    } else if (op == 1){
      if (tid < A_) C[(PROJ0+t)*65 + tid] += metaAll[(b*LP+t)*A_ + tid];
    }
    if (opn == 2){
      float* Un = Ul[(t+1)&1];
      #pragma unroll
      for (int k=0;k<5;k++){
        int i = tid*4 + k*1024;
        int r = i/80, c = i%80;
        Un[r*81+c]   = rv0[k].x+rv1[k].x; Un[r*81+c+1] = rv0[k].y+rv1[k].y;
        Un[r*81+c+2] = rv0[k].z+rv1[k].z; Un[r*81+c+3] = rv0[k].w+rv1[k].w;
      }
    }
    __syncthreads();
  }
  for (int i=tid;i<QC*A_;i+=256) Cm[b*QC*A_ + i] = C[(i>>6)*65 + (i&63)];
}

// ---------------- k_out v3: MFMA, wide grid ----------------
__global__ __launch_bounds__(256) void k_out(const unsigned short* QTf, const float* Cm,
                                             float* ol, float* esum){
  __shared__ float Cpad[QC*65];
  __shared__ float wsum[4];
  int b = blockIdx.x / 66, rem = blockIdx.x % 66;
  int tid = threadIdx.x;
  int w = tid >> 6, l = tid & 63, quad = l >> 4, lq = l & 15;
  for (int i=tid; i<QC*A_; i+=256) Cpad[(i>>6)*65 + (i&63)] = Cm[b*QC*A_ + i];
  __syncthreads();
  U8 bfr[3][4];
  #pragma unroll
  for (int kk=0;kk<3;kk++){
    #pragma unroll
    for (int at=0;at<4;at++){
      float v[8];
      #pragma unroll
      for (int jj=0;jj<8;jj++){
        int j = kk*32 + quad*8 + jj;
        v[jj] = (j < QC) ? Cpad[j*65 + at*16 + lq] : 0.f;
      }
      #pragma unroll
      for (int d=0;d<4;d++) bfr[kk][at].u[d] = pack2(v[2*d], v[2*d+1]);
    }
  }
  const unsigned short* Qb = QTf + (size_t)b*QTF_B;
  int mt = rem*4 + w;
  int nb = (mt>>1)*512 + (mt&1)*16 + lq;        // A lane row = lq
  f32x4 acc[4];
  #pragma unroll
  for (int at=0;at<4;at++) acc[at] = (f32x4){0.f,0.f,0.f,0.f};
  #pragma unroll
  for (int kk=0;kk<3;kk++){
    U8 af;
    #pragma unroll
    for (int d=0;d<4;d++){
      int j0 = kk*32 + quad*8 + 2*d;
      int j1 = j0 + 1;
      unsigned u0 = (j0 < QC) ? (unsigned)Qb[(j0>>4)*QTF_C + (j0&15)*32 + nb] : 0u;
      unsigned u1 = (j1 < QC) ? (unsigned)Qb[(j1>>4)*QTF_C + (j1&15)*32 + nb] : 0u;
      af.u[d] = u0 | (u1 << 16);
    }
    #pragma unroll
    for (int at=0;at<4;at++)
      acc[at] = __builtin_amdgcn_mfma_f32_16x16x32_bf16(af.v, bfr[kk][at].v, acc[at], 0, 0, 0);
  }
  float le = 0.f;
  #pragma unroll
  for (int r=0;r<4;r++){
    float s = 0.f;
    #pragma unroll
    for (int at=0;at<4;at++) s = fmaf(acc[at][r], acc[at][r], s);
    s += __shfl_xor(s, 1, 64);
    s += __shfl_xor(s, 2, 64);
    s += __shfl_xor(s, 4, 64);
    s += __shfl_xor(s, 8, 64);
    if (lq == 0){
      float o = s * (1.f/A_);
      ol[(size_t)b*NN + mt*16 + quad*4 + r] = o;
      le += expf(o);
    }
  }
  le += __shfl_down(le, 32, 64);
  le += __shfl_down(le, 16, 64);
  if (l == 0) wsum[w] = le;
  __syncthreads();
  if (tid == 0) atomicAdd(&esum[b], wsum[0]+wsum[1]+wsum[2]+wsum[3]);
}

// ---------------- k_fin ----------------
__global__ void k_fin(const float* ol, const float* esum, const int* flag, void* out){
  int idx = blockIdx.x*256 + threadIdx.x;
  if (idx < B_*NN){
    int b = idx / NN;
    float v = ol[idx] - logf(esum[b]);
    if (*flag) ((float*)out)[idx] = v;
    else       ((bf16*)out)[idx]  = __float2bfloat16(v);
  }
}

extern "C" void kernel_launch(void* const* d_in, const int* in_sizes, int n_in,
                              void* d_out, int out_size, void* d_ws, size_t ws_size,
                              hipStream_t stream) {
  (void)in_sizes; (void)n_in; (void)out_size; (void)ws_size;
  const int* ops  = (const int*)d_in[17];
  const int* args = (const int*)d_in[18];
  const int* gtc  = (const int*)d_in[19];
  const int* gta  = (const int*)d_in[20];

  float* ws = (float*)d_ws;
  int* flag = (int*)ws;
  float* W  = ws + 16;

  const float* meta_init  = W + 589824;
  const float* att_init   = W + 589888;
  const float* aw1        = W + 589952;
  const float* ab1        = W + 622720;
  const float* aw2        = W + 622976;
  const float* ab2        = W + 639360;
  const float* mw1        = W + 639424;
  const float* mb1        = W + 672192;
  const float* mw2        = W + 672448;
  const float* mb2        = W + 688832;

  constexpr size_t OFF_OBJIN   = 16 + TOT_IN;            // 688912
  constexpr size_t OFF_OBJOUT  = OFF_OBJIN  + 65536;
  constexpr size_t OFF_METAALL = OFF_OBJOUT + 65536;
  constexpr size_t OFF_METAH   = OFF_METAALL + 6144;
  constexpr size_t OFF_QSUM    = OFF_METAH  + 24576;
  constexpr size_t OFF_ESUM    = OFF_QSUM   + 640;
  constexpr size_t OFF_UT0     = OFF_ESUM   + 16;
  constexpr size_t OFF_UT1     = OFF_UT0    + 491520;
  constexpr size_t OFF_CM      = OFF_UT1    + 491520;
  constexpr size_t OFF_OL      = OFF_CM     + 40960;
  constexpr size_t OFF_QTF     = OFF_OL     + 33792;
  constexpr size_t OFF_AOPTC   = OFF_QTF    + 1351680;
  constexpr size_t OFF_AOPTO   = OFF_AOPTC  + 524288;
  constexpr size_t OFF_AWF     = OFF_AOPTO  + 131072;
  constexpr size_t OFF_TB      = OFF_AWF    + 8192;      // 8 partials x 983040 dwords
  // end = OFF_TB + 7864320 = 11,788,704 floats ~= 47.2 MB (ws is 256 MiB)

  float* objIn   = ws + OFF_OBJIN;
  float* objOut  = ws + OFF_OBJOUT;
  float* metaAll = ws + OFF_METAALL;
  float* metaH   = ws + OFF_METAH;
  float* qsum    = ws + OFF_QSUM;
  float* esum    = ws + OFF_ESUM;
  float* Ut0     = ws + OFF_UT0;
  float* Ut1     = ws + OFF_UT1;
  float* Cm      = ws + OFF_CM;
  float* ol      = ws + OFF_OL;
  unsigned short* QTf    = (unsigned short*)(ws + OFF_QTF);
  unsigned short* AoptC  = (unsigned short*)(ws + OFF_AOPTC);
  unsigned short* AoptO  = (unsigned short*)(ws + OFF_AOPTO);
  unsigned short* awFrag = (unsigned short*)(ws + OFF_AWF);
  unsigned* TB           = (unsigned*)(ws + OFF_TB);

  Ptr16 ps;
  const int src_idx[16] = {0,1,2,3,4,5,6,8,9,10,11,12,13,14,15,16};
  for (int i=0;i<16;i++) ps.p[i] = d_in[src_idx[i]];

  k_prep<<<482, 256, 0, stream>>>(ps, flag, W, awFrag, gtc, gta, objIn, objOut, qsum);
  k_mid <<<224, 256, 0, stream>>>(ps, flag, meta_init, mw1, mb1, mw2, mb2,
                                  aw1, ab1, ops, args, objIn, objOut, awFrag,
                                  metaAll, metaH, QTf, qsum, AoptC, AoptO);
  k_T   <<<B_*LP*4*8, 64, 0, stream>>>(AoptC, AoptO, QTf, metaH, ops, TB);
  k_U   <<<B_*LP*2, 256, 0, stream>>>(TB, aw2, ab2, qsum, ops, Ut0, Ut1);
  k_rec <<<B_, 256, 0, stream>>>(Ut0, Ut1, metaAll, ops, att_init, Cm);
  k_out <<<B_*66, 256, 0, stream>>>(QTf, Cm, ol, esum);
  k_fin <<<(B_*NN + 255)/256, 256, 0, stream>>>(ol, esum, flag, d_out);
}

// Round 11
// 217.145 us; speedup vs baseline: 1.0589x; 1.0589x over previous
//
#include <hip/hip_runtime.h>
#include <hip/hip_bf16.h>

typedef __hip_bfloat16 bf16;
typedef float f32x4 __attribute__((ext_vector_type(4)));
typedef short s16x8 __attribute__((ext_vector_type(8)));

#define B_    8
#define LP    12
#define NC    4096
#define NO    128
#define NAPO  8
#define NN    4224
#define E_    64
#define A_    64
#define H_    256
#define QC    80
#define PROJ0 65
#define NCHUNK 17

#define TOT_IN 688896
#define QTF_C  67584     // 132*512 shorts per (b,c) group
#define QTF_B  337920    // 5*QTF_C per batch
#define TB_P   983040    // dwords per kh-partial: 96*4*2560

struct Ptr16 { const void* p[16]; };
union U8 { s16x8 v; unsigned u[4]; };

__device__ __forceinline__ float b2f(bf16 x){ return __bfloat162float(x); }
__device__ __forceinline__ float bs2f(unsigned short s){
  union { unsigned u; float f; } x; x.u = ((unsigned)s) << 16; return x.f;
}
__device__ __forceinline__ unsigned short f2bs(float f){
  bf16 h = __float2bfloat16(f);
  union { bf16 h; unsigned short s; } x; x.h = h; return x.s;
}
__device__ __forceinline__ unsigned pack2(float a, float b){
  return (unsigned)f2bs(a) | ((unsigned)f2bs(b) << 16);
}
__device__ __forceinline__ float lo16f(unsigned w){
  union { unsigned u; float f; } x; x.u = w << 16; return x.f;
}
__device__ __forceinline__ float hi16f(unsigned w){
  union { unsigned u; float f; } x; x.u = w & 0xffff0000u; return x.f;
}
__device__ __forceinline__ float rdval(const void* p, size_t i, int fl){
  return fl ? ((const float*)p)[i] : bs2f(((const unsigned short*)p)[i]);
}

// ---------------- k_prep v4: concept tensors NOT converted; obj gather branch-hoisted ----------------
__global__ void k_prep(Ptr16 ps, int* flag, float* dst,
                       unsigned short* awFrag,
                       const int* gtc, const int* gta,
                       float* objIn, float* objOut, float* qsum_esum){
  int tid = threadIdx.x;
  // wave-local dtype detect: probe concept_embIn even half-words; fp32 garbage -> ~46% exp>=137
  const unsigned short* u = (const unsigned short*)ps.p[4];
  int hit = (((u[tid*16] >> 7) & 0xFF) >= 137) ? 1 : 0;
  unsigned long long m = __ballot(hit);
  int fl = (m != 0ULL) ? 1 : 0;
  int mb = blockIdx.x;
  if (mb < 161){
    int qi = mb*256 + tid;
    if (qi >= 41152) return;
    int idx = (qi < 16384) ? qi*4 : qi*4 + 524288;   // skip concept tensors [65536,589824)
    constexpr int cum[17] = {0,16384,32768,49152,65536,327680,589824,589888,589952,
                             622720,622976,639360,639424,672192,672448,688832,688896};
    int t = 0;
    #pragma unroll
    for (int i=1;i<16;i++) if (idx >= cum[i]) t = i;
    int off = idx - cum[t];
    float4 v;
    if (fl){
      v = *(const float4*)((const float*)ps.p[t] + off);
    } else {
      uint2 sv = *(const uint2*)((const unsigned short*)ps.p[t] + off);
      v.x = lo16f(sv.x); v.y = hi16f(sv.x);
      v.z = lo16f(sv.y); v.w = hi16f(sv.y);
    }
    *(float4*)(dst + idx) = v;
  } else if (mb < 225){
    int idx = (mb-161)*256 + tid;               // < 16384
    int j = idx & 7;
    int lane = (idx >> 3) & 63;
    int mm = (idx >> 9) & 15;
    int kc = idx >> 13;
    int e = kc*32 + (lane>>4)*8 + j;
    int h = mm*16 + (lane&15);
    awFrag[idx] = f2bs(rdval(ps.p[8], (size_t)e*H_ + h, fl));
  } else if (mb < 481){
    int idx = (mb-225)*256 + tid;               // < 65536
    int e = idx & 63; int bo = idx >> 6;
    int cls = gtc[bo];
    const int* ga = gta + bo*NAPO;
    float vi, vo;
    if (fl){
      const float* p0 = (const float*)ps.p[0];
      const float* p1 = (const float*)ps.p[1];
      const float* p2 = (const float*)ps.p[2];
      const float* p3 = (const float*)ps.p[3];
      vi = p0[(size_t)cls*E_ + e];
      vo = p1[(size_t)cls*E_ + e];
      #pragma unroll
      for (int j=0;j<NAPO;j++){
        int at = ga[j];
        vi += p2[(size_t)at*E_ + e];
        vo += p3[(size_t)at*E_ + e];
      }
    } else {
      const unsigned short* p0 = (const unsigned short*)ps.p[0];
      const unsigned short* p1 = (const unsigned short*)ps.p[1];
      const unsigned short* p2 = (const unsigned short*)ps.p[2];
      const unsigned short* p3 = (const unsigned short*)ps.p[3];
      vi = bs2f(p0[(size_t)cls*E_ + e]);
      vo = bs2f(p1[(size_t)cls*E_ + e]);
      #pragma unroll
      for (int j=0;j<NAPO;j++){
        int at = ga[j];
        vi += bs2f(p2[(size_t)at*E_ + e]);
        vo += bs2f(p3[(size_t)at*E_ + e]);
      }
    }
    objIn[idx] = vi; objOut[idx] = vo;
  } else {
    if (tid < 656) qsum_esum[tid] = 0.f;        // qsum(640) + esum(16)
    if (tid == 0) *flag = fl;
  }
}

// ================ k_mid: meta(8) | QTf+qsum(136) | baseT->Aopt(80) ================
// mid_meta v3: op-skip + raw concept reads (argx only; weights are converted).
__device__ __forceinline__ void mid_meta(char* smem, int b, int fl, const void* coRaw,
                       const float* meta_init,
                       const float* mw1, const float* mb1, const float* mw2, const float* mb2,
                       const float* aw1, const float* ab1,
                       const int* ops, const int* args,
                       float* metaAll, float* metaH){
  unsigned* mw1p = (unsigned*)smem;               // 64*256 = 65536 B
  unsigned* mw2p = (unsigned*)(smem + 65536);     // 128*64 = 32768 B
  unsigned* aw1p = (unsigned*)(smem + 98304);     // 32*256 = 32768 B
  float* meta_s  = (float*)(smem + 131072);
  float* argx    = (float*)(smem + 131328);
  float* hid     = (float*)(smem + 131584);
  float* part    = (float*)(smem + 132608);
  int tid = threadIdx.x;

  for (int i=tid; i<64*256; i+=256){
    int j2 = i >> 8, t = i & 255;
    mw1p[i] = pack2(mw1[(2*j2)*H_ + t], mw1[(2*j2+1)*H_ + t]);
  }
  for (int i=tid; i<128*64; i+=256){
    int h2 = i >> 6, a = i & 63;
    mw2p[i] = pack2(mw2[(2*h2)*A_ + a], mw2[(2*h2+1)*A_ + a]);
  }
  for (int i=tid; i<32*256; i+=256){
    int a2 = i >> 8, t = i & 255;
    aw1p[i] = pack2(aw1[(E_+2*a2)*H_ + t], aw1[(E_+2*a2+1)*H_ + t]);
  }
  float r_mb1 = mb1[tid];
  float r_ab1 = ab1[tid];
  float r_mb2 = (tid < A_) ? mb2[tid] : 0.f;
  if (tid < A_) meta_s[tid] = meta_init[tid];
  __syncthreads();

  // initial metaH (from initial meta)
  float mh = r_ab1;
  for (int a2=0;a2<32;a2++){
    unsigned w = aw1p[a2*256 + tid];
    float2 mp = *(const float2*)&meta_s[2*a2];
    mh = fmaf(mp.x, lo16f(w), mh);
    mh = fmaf(mp.y, hi16f(w), mh);
  }

  for (int t=0;t<LP;t++){
    int op  = ops[b*LP + t];
    if (op == 0){
      int arg = args[b*LP + t];
      if (tid >= 64 && tid < 128) argx[tid-64] = rdval(coRaw, (size_t)arg*E_ + (tid-64), fl);
      __syncthreads();
      float acc = r_mb1;
      for (int j2=0;j2<32;j2++){
        unsigned w = mw1p[j2*256 + tid];
        float2 xp = *(const float2*)&meta_s[2*j2];
        acc = fmaf(xp.x, lo16f(w), acc);
        acc = fmaf(xp.y, hi16f(w), acc);
      }
      for (int j2=0;j2<32;j2++){
        unsigned w = mw1p[(32+j2)*256 + tid];
        float2 xp = *(const float2*)&argx[2*j2];
        acc = fmaf(xp.x, lo16f(w), acc);
        acc = fmaf(xp.y, hi16f(w), acc);
      }
      hid[tid] = fmaxf(acc, 0.f);
      __syncthreads();
      int wv_ = tid >> 6, l = tid & 63;
      float acc2 = 0.f;
      for (int h2 = wv_*32; h2 < wv_*32+32; h2++){
        unsigned w = mw2p[h2*64 + l];
        float2 hp = *(const float2*)&hid[2*h2];
        acc2 = fmaf(hp.x, lo16f(w), acc2);
        acc2 = fmaf(hp.y, hi16f(w), acc2);
      }
      part[wv_*64 + l] = acc2;
      __syncthreads();
      if (tid < A_){
        float s = part[tid] + part[64+tid] + part[128+tid] + part[192+tid] + r_mb2;
        meta_s[tid] = s;
      }
      __syncthreads();
      mh = r_ab1;
      for (int a2=0;a2<32;a2++){
        unsigned w = aw1p[a2*256 + tid];
        float2 mp = *(const float2*)&meta_s[2*a2];
        mh = fmaf(mp.x, lo16f(w), mh);
        mh = fmaf(mp.y, hi16f(w), mh);
      }
    }
    if (tid < A_) metaAll[(b*LP+t)*A_ + tid] = meta_s[tid];
    metaH[(b*LP+t)*H_ + tid] = mh;
  }
}

// mid_qt v4: branch-hoisted typed staging loops + column-sum reduction + proj-skip
__device__ __forceinline__ void mid_qt(char* smem, int idx, int fl,
                       const void* ciRaw, const void* coRaw, const int* args,
                       const float* objIn, const float* objOut, const int* ops,
                       unsigned short* QTf, float* qsum){
  float* tile = (float*)smem;                  // 256*65*4 = 66560 B
  float* argv = (float*)(smem + 66560);        // 3072 B
  float* qs   = (float*)(smem + 69632);        // 320 B
  float* colp = (float*)(smem + 69952);        // 1024 B
  int b = idx / NCHUNK, chunk = idx % NCHUNK;
  int tid = threadIdx.x;
  int rows = (chunk < 16) ? 256 : 128;
  int n0 = chunk*256;
  int n = n0 + tid;
  bool valid = (tid < rows);
  if (tid < 80) qs[tid] = 0.f;
  int opsv[LP];
  #pragma unroll
  for (int t=0;t<LP;t++) opsv[t] = ops[b*LP + t];
  unsigned short* Qb = QTf + (size_t)b*QTF_B + ((n>>5)*512 + (n&31));
  {
    int tot = rows*64;
    if (chunk < 16){
      if (fl){
        const float* src = (const float*)ciRaw + (size_t)n0*E_;
        for (int i=tid; i<tot; i+=256) tile[(i>>6)*65 + (i&63)] = src[i];
      } else {
        const unsigned short* src = (const unsigned short*)ciRaw + (size_t)n0*E_;
        for (int i=tid; i<tot; i+=256) tile[(i>>6)*65 + (i&63)] = bs2f(src[i]);
      }
    } else {
      const float* src = objIn + (size_t)b*NO*E_;
      for (int i=tid; i<tot; i+=256) tile[(i>>6)*65 + (i&63)] = src[i];
    }
  }
  __syncthreads();
  if (valid){
    Qb[0] = 0x3F80;
    Qb[4*QTF_C + 13*32] = 0;
    Qb[4*QTF_C + 14*32] = 0;
    Qb[4*QTF_C + 15*32] = 0;
    for (int e=0;e<64;e++){
      int qc = 1+e;
      Qb[(qc>>4)*QTF_C + (qc&15)*32] = f2bs(tile[tid*65 + e]);
    }
  }
  // column sums via row-groups (replaces 64 LDS atomics/thread)
  {
    int col = tid & 63, rg = tid >> 6;
    float s = 0.f;
    int r0 = rg*64; int r1 = r0+64; if (r1 > rows) r1 = rows;
    for (int r=r0; r<r1; r++) s += tile[r*65 + col];
    colp[rg*64 + col] = s;
  }
  __syncthreads();
  if (tid < 64) qs[1+tid] = colp[tid] + colp[64+tid] + colp[128+tid] + colp[192+tid];
  if (fl){
    const float* co = (const float*)coRaw;
    for (int i=tid;i<LP*E_;i+=256) argv[i] = co[(size_t)args[b*LP + (i>>6)]*E_ + (i&63)];
  } else {
    const unsigned short* co = (const unsigned short*)coRaw;
    for (int i=tid;i<LP*E_;i+=256) argv[i] = bs2f(co[(size_t)args[b*LP + (i>>6)]*E_ + (i&63)]);
  }
  {
    int tot = rows*64;
    if (chunk < 16){
      if (fl){
        const float* src = (const float*)coRaw + (size_t)n0*E_;
        for (int i=tid; i<tot; i+=256) tile[(i>>6)*65 + (i&63)] = src[i];
      } else {
        const unsigned short* src = (const unsigned short*)coRaw + (size_t)n0*E_;
        for (int i=tid; i<tot; i+=256) tile[(i>>6)*65 + (i&63)] = bs2f(src[i]);
      }
    } else {
      const float* src = objOut + (size_t)b*NO*E_;
      for (int i=tid; i<tot; i+=256) tile[(i>>6)*65 + (i&63)] = src[i];
    }
  }
  __syncthreads();
  float dots[LP];
  #pragma unroll
  for (int t=0;t<LP;t++) dots[t] = 0.f;
  for (int e=0;e<64;e++){
    float o = tile[tid*65 + e];
    #pragma unroll
    for (int t=0;t<LP;t++) dots[t] += o*argv[t*64+e];
  }
  #pragma unroll
  for (int t=0;t<LP;t++){
    int opt = opsv[t];
    float v = (valid && opt == 1) ? dots[t]*(1.f/E_) : 0.f;
    if (valid){
      int qc = PROJ0+t;
      Qb[(qc>>4)*QTF_C + (qc&15)*32] = f2bs(v);
    }
    if (opt == 1){
      float r = v;
      #pragma unroll
      for (int off=32; off>0; off>>=1) r += __shfl_down(r, off, 64);
      if ((tid & 63) == 0) atomicAdd(&qs[PROJ0+t], r);
    }
  }
  __syncthreads();
  if (tid < 80) atomicAdd(&qsum[b*QC + tid], qs[tid]);
  if (chunk == 0 && tid == 0) atomicAdd(&qsum[b*QC], (float)NN);
}

// mid_base v2: raw conceptOut reads (bf16 path loads s16x8 directly)
__device__ __forceinline__ void mid_base(int blk, int fl, const void* coRaw,
                       const float* objOut,
                       const unsigned short* awFrag,
                       unsigned short* AoptC, unsigned short* AoptO){
  int n0 = blk * 64;
  int tid = threadIdx.x;
  int w = tid >> 6, l = tid & 63, quad = l >> 4, lq = l & 15;
  int n = n0 + w*16 + lq;
  f32x4 acc[16];
  #pragma unroll
  for (int m=0;m<16;m++) acc[m] = (f32x4){0.f,0.f,0.f,0.f};
  #pragma unroll
  for (int kc=0;kc<2;kc++){
    s16x8 bfr;
    size_t eoff = (size_t)0 + kc*32 + quad*8;
    if (n < NC){
      if (fl){
        const float* src = (const float*)coRaw + (size_t)n*E_;
        #pragma unroll
        for (int j=0;j<8;j++) bfr[j] = (short)f2bs(src[eoff + j]);
      } else {
        bfr = *(const s16x8*)((const unsigned short*)coRaw + (size_t)n*E_ + eoff);
      }
    } else {
      const float* src = objOut + (size_t)(n-NC)*E_;
      #pragma unroll
      for (int j=0;j<8;j++) bfr[j] = (short)f2bs(src[eoff + j]);
    }
    const unsigned short* ap = awFrag + ((size_t)(kc*16)*64 + l)*8;
    #pragma unroll
    for (int m=0;m<16;m++){
      s16x8 af = *(const s16x8*)(ap + (size_t)m*64*8);
      acc[m] = __builtin_amdgcn_mfma_f32_16x16x32_bf16(af, bfr, acc[m], 0, 0, 0);
    }
  }
  int nl = n & 31;
  if (n < NC){
    int nch = n >> 5;
    #pragma unroll
    for (int m=0;m<16;m++){
      #pragma unroll
      for (int r=0;r<4;r++)
        AoptC[(size_t)(m*128 + nch)*512 + (quad*4+r)*32 + nl] = f2bs(acc[m][r]);
    }
  } else {
    int no = n - NC; int bb = no >> 7; int oc = (no & 127) >> 5;
    #pragma unroll
    for (int m=0;m<16;m++){
      #pragma unroll
      for (int r=0;r<4;r++)
        AoptO[(size_t)((bb*16 + m)*4 + oc)*512 + (quad*4+r)*32 + nl] = f2bs(acc[m][r]);
    }
  }
}

__global__ __launch_bounds__(256) void k_mid(
    Ptr16 ps, const int* flag,
    const float* meta_init, const float* mw1, const float* mb1, const float* mw2, const float* mb2,
    const float* aw1, const float* ab1, const int* ops, const int* args,
    const float* objIn, const float* objOut, const unsigned short* awFrag,
    float* metaAll, float* metaH, unsigned short* QTf, float* qsum,
    unsigned short* AoptC, unsigned short* AoptO){
  __shared__ __align__(16) char smem[133888];
  int fl = *flag;
  const void* ciRaw = ps.p[4];
  const void* coRaw = ps.p[5];
  int mb = blockIdx.x;
  if (mb < 8)
    mid_meta(smem, mb, fl, coRaw, meta_init, mw1, mb1, mw2, mb2, aw1, ab1, ops, args, metaAll, metaH);
  else if (mb < 144)
    mid_qt(smem, mb-8, fl, ciRaw, coRaw, args, objIn, objOut, ops, QTf, qsum);
  else
    mid_base(mb-144, fl, coRaw, objOut, awFrag, AoptC, AoptO);
}

// ---------------- k_T v7: single-wave blocks, kh 8-way K-split + op-skip ----------------
__global__ __launch_bounds__(64) void k_T(const unsigned short* AoptC, const unsigned short* AoptO,
                                          const unsigned short* QTf, const float* metaH,
                                          const int* ops, unsigned* TB){
  int bid = blockIdx.x;
  int kh = bid & 7; int ht = (bid >> 3) & 3; int bt = bid >> 5; int b = bt / LP;
  if (ops[bt] != 2) return;
  int l = threadIdx.x, quad = l >> 4, lq = l & 15;
  int off = lq*32 + quad*8;
  int start = (kh < 4) ? (kh*17) : (68 + (kh-4)*16);
  int count = (kh < 4) ? 17 : 16;
  float mh[4];
  #pragma unroll
  for (int s=0;s<4;s++) mh[s] = metaH[(size_t)bt*H_ + ht*64 + s*16 + lq];
  f32x4 acc[4][5];
  #pragma unroll
  for (int s=0;s<4;s++){
    #pragma unroll
    for (int c=0;c<5;c++) acc[s][c] = (f32x4){0.f,0.f,0.f,0.f};
  }
  const unsigned short* QTb = QTf + (size_t)b*QTF_B + off;
  const unsigned short* AC  = AoptC + (size_t)(ht*4)*65536 + off;       // 65536 = 128*512
  const unsigned short* AO  = AoptO + (size_t)(b*16 + ht*4)*2048 + off; // 2048 = 4*512
  for (int it=0; it<count; it++){
    int nchunk = start + it;
    U8 bfr[5];
    #pragma unroll
    for (int c=0;c<5;c++)
      bfr[c].v = *(const s16x8*)(QTb + (size_t)c*QTF_C + (size_t)nchunk*512);
    bool isC = (nchunk < 128);
    #pragma unroll
    for (int s=0;s<4;s++){
      U8 a;
      a.v = isC ? *(const s16x8*)(AC + (size_t)s*65536 + (size_t)nchunk*512)
                : *(const s16x8*)(AO + (size_t)s*2048 + (size_t)(nchunk-128)*512);
      float mhs = mh[s];
      U8 af;
      #pragma unroll
      for (int d=0;d<4;d++){
        unsigned wv = a.u[d];
        float lo = fmaxf(__uint_as_float(wv << 16) + mhs, 0.f);
        float hi = fmaxf(__uint_as_float(wv & 0xffff0000u) + mhs, 0.f);
        af.u[d] = __builtin_amdgcn_perm(__float_as_uint(hi), __float_as_uint(lo), 0x07060302u);
      }
      #pragma unroll
      for (int c=0;c<5;c++)
        acc[s][c] = __builtin_amdgcn_mfma_f32_16x16x32_bf16(af.v, bfr[c].v, acc[s][c], 0, 0, 0);
    }
  }
  unsigned* Tp = TB + (size_t)kh*TB_P + ((size_t)bt*4 + ht)*2560;
  #pragma unroll
  for (int s=0;s<4;s++){
    #pragma unroll
    for (int c=0;c<5;c++){
      uint2 v;
      v.x = pack2(acc[s][c][0], acc[s][c][1]);
      v.y = pack2(acc[s][c][2], acc[s][c][3]);
      *(uint2*)(Tp + (s*5+c)*128 + l*2) = v;
    }
  }
}

// ---------------- k_U v4: K-split x2 + op-skip ----------------
__global__ __launch_bounds__(256) void k_U(const unsigned* TB,
                                           const float* w2, const float* b2v,
                                           const float* qsum, const int* ops,
                                           float* Ut0, float* Ut1){
  __shared__ float Wt[128*64];
  __shared__ float Tt[128*81];
  int bid = blockIdx.x;
  int kq = bid & 1; int bt = bid >> 1; int b = bt / LP;
  if (ops[bt] != 2) return;
  int tid = threadIdx.x;
  for (int i=tid; i<8192; i+=256){
    int hl = i >> 6, e = i & 63;
    Wt[i] = w2[(kq*128 + hl)*E_ + e];
  }
  #pragma unroll
  for (int half=0; half<2; half++){
    const unsigned* base = TB + ((size_t)bt*4 + kq*2 + half)*2560;
    for (int i2=tid; i2<2560; i2+=256){
      float lo = 0.f, hi = 0.f;
      #pragma unroll
      for (int p=0;p<8;p++){
        unsigned w = base[(size_t)p*TB_P + i2];
        lo += lo16f(w); hi += hi16f(w);
      }
      int idx = 2*i2;
      int sc = idx >> 8; int ll = (idx >> 2) & 63; int r = idx & 3;
      int s = sc/5, c = sc - s*5;
      int hl = half*64 + s*16 + ((ll>>4)<<2) + r;
      int qc = c*16 + (ll&15);
      Tt[hl*81 + qc]     = lo;
      Tt[(hl+1)*81 + qc] = hi;
    }
  }
  __syncthreads();
  int el = tid & 15, ql = tid >> 4;
  float acc[4][5];
  #pragma unroll
  for (int i=0;i<4;i++){
    #pragma unroll
    for (int j=0;j<5;j++) acc[i][j]=0.f;
  }
  #pragma unroll 4
  for (int kk=0; kk<128; kk++){
    float4 wv = *(const float4*)&Wt[kk*64 + el*4];
    float ww[4] = {wv.x, wv.y, wv.z, wv.w};
    const float* tp = &Tt[kk*81 + ql*5];
    #pragma unroll
    for (int j=0;j<5;j++){
      float tv = tp[j];
      #pragma unroll
      for (int i=0;i<4;i++) acc[i][j] = fmaf(ww[i], tv, acc[i][j]);
    }
  }
  const float invN = 1.f/NN;
  float* Up = (kq ? Ut1 : Ut0) + (size_t)bt*5120;
  if (kq == 0){
    float be[4], qv[5];
    #pragma unroll
    for (int i=0;i<4;i++) be[i] = b2v[el*4+i];
    #pragma unroll
    for (int j=0;j<5;j++) qv[j] = qsum[b*QC + ql*5+j];
    #pragma unroll
    for (int i=0;i<4;i++){
      #pragma unroll
      for (int j=0;j<5;j++)
        Up[(el*4+i)*QC + ql*5+j] = (acc[i][j] + be[i]*qv[j]) * invN;
    }
  } else {
    #pragma unroll
    for (int i=0;i<4;i++){
      #pragma unroll
      for (int j=0;j<5;j++)
        Up[(el*4+i)*QC + ql*5+j] = acc[i][j] * invN;
    }
  }
}

// ---------------- k_rec v6: op-skip + gated Ul prefetch ----------------
__global__ __launch_bounds__(256) void k_rec(const float* Ut0, const float* Ut1, const float* metaAll,
                                             const int* ops, const float* att_init, float* Cm){
  __shared__ float C[QC*65];
  __shared__ float Ul[2][64*81];
  int b = blockIdx.x, tid = threadIdx.x;
  int w = tid >> 6, l = tid & 63, quad = l >> 4, lq = l & 15;
  for (int i=tid;i<QC*65;i+=256) C[i] = 0.f;
  if (tid < A_) C[tid] = att_init[tid];
  if (ops[b*LP] == 2){
    const float* U0 = Ut0 + (size_t)(b*LP)*5120;
    const float* U1 = Ut1 + (size_t)(b*LP)*5120;
    #pragma unroll
    for (int k=0;k<5;k++){
      int i = tid*4 + k*1024;
      float4 v0 = *(const float4*)&U0[i];
      float4 v1 = *(const float4*)&U1[i];
      int r = i/80, c = i%80;
      Ul[0][r*81+c]   = v0.x+v1.x; Ul[0][r*81+c+1] = v0.y+v1.y;
      Ul[0][r*81+c+2] = v0.z+v1.z; Ul[0][r*81+c+3] = v0.w+v1.w;
    }
  }
  __syncthreads();
  for (int t=0;t<LP;t++){
    int opn = (t < LP-1) ? ops[b*LP + t + 1] : 0;
    float4 rv0[5], rv1[5];
    if (opn == 2){
      const float* U0 = Ut0 + (size_t)(b*LP+t+1)*5120;
      const float* U1 = Ut1 + (size_t)(b*LP+t+1)*5120;
      #pragma unroll
      for (int k=0;k<5;k++){
        rv0[k] = *(const float4*)&U0[tid*4 + k*1024];
        rv1[k] = *(const float4*)&U1[tid*4 + k*1024];
      }
    }
    int op = ops[b*LP + t];
    f32x4 acc[4];
    if (op == 2){
      const float* Uc = Ul[t&1];
      U8 af[3][4];
      #pragma unroll
      for (int k0t=0;k0t<3;k0t++){
        #pragma unroll
        for (int s=0;s<4;s++){
          int e = s*16 + lq;
          int qb = k0t*32 + quad*8;
          float v[8];
          #pragma unroll
          for (int j=0;j<8;j++){
            int qc = qb + j;
            v[j] = (qc < QC) ? Uc[e*81 + qc] : 0.f;
          }
          #pragma unroll
          for (int d=0;d<4;d++) af[k0t][s].u[d] = pack2(v[2*d], v[2*d+1]);
        }
      }
      U8 bf[3];
      #pragma unroll
      for (int k0t=0;k0t<3;k0t++){
        int kb = k0t*32 + quad*8;
        float v[8];
        #pragma unroll
        for (int j=0;j<8;j++){
          int k = kb + j;
          v[j] = (k < QC) ? C[k*65 + w*16 + lq] : 0.f;
        }
        #pragma unroll
        for (int d=0;d<4;d++) bf[k0t].u[d] = pack2(v[2*d], v[2*d+1]);
      }
      #pragma unroll
      for (int s=0;s<4;s++){
        acc[s] = (f32x4){0.f,0.f,0.f,0.f};
        #pragma unroll
        for (int k0t=0;k0t<3;k0t++)
          acc[s] = __builtin_amdgcn_mfma_f32_16x16x32_bf16(af[k0t][s].v, bf[k0t].v, acc[s], 0, 0, 0);
      }
    }
    __syncthreads();
    if (op == 2){
      #pragma unroll
      for (int s=0;s<4;s++){
        #pragma unroll
        for (int r=0;r<4;r++){
          int e = s*16 + quad*4 + r;
          C[(1+e)*65 + w*16 + lq] += acc[s][r];
        }
      }
    } else if (op == 1){
      if (tid < A_) C[(PROJ0+t)*65 + tid] += metaAll[(b*LP+t)*A_ + tid];
    }
    if (opn == 2){
      float* Un = Ul[(t+1)&1];
      #pragma unroll
      for (int k=0;k<5;k++){
        int i = tid*4 + k*1024;
        int r = i/80, c = i%80;
        Un[r*81+c]   = rv0[k].x+rv1[k].x; Un[r*81+c+1] = rv0[k].y+rv1[k].y;
        Un[r*81+c+2] = rv0[k].z+rv1[k].z; Un[r*81+c+3] = rv0[k].w+rv1[k].w;
      }
    }
    __syncthreads();
  }
  for (int i=tid;i<QC*A_;i+=256) Cm[b*QC*A_ + i] = C[(i>>6)*65 + (i&63)];
}

// ---------------- k_out v3: MFMA, wide grid ----------------
__global__ __launch_bounds__(256) void k_out(const unsigned short* QTf, const float* Cm,
                                             float* ol, float* esum){
  __shared__ float Cpad[QC*65];
  __shared__ float wsum[4];
  int b = blockIdx.x / 66, rem = blockIdx.x % 66;
  int tid = threadIdx.x;
  int w = tid >> 6, l = tid & 63, quad = l >> 4, lq = l & 15;
  for (int i=tid; i<QC*A_; i+=256) Cpad[(i>>6)*65 + (i&63)] = Cm[b*QC*A_ + i];
  __syncthreads();
  U8 bfr[3][4];
  #pragma unroll
  for (int kk=0;kk<3;kk++){
    #pragma unroll
    for (int at=0;at<4;at++){
      float v[8];
      #pragma unroll
      for (int jj=0;jj<8;jj++){
        int j = kk*32 + quad*8 + jj;
        v[jj] = (j < QC) ? Cpad[j*65 + at*16 + lq] : 0.f;
      }
      #pragma unroll
      for (int d=0;d<4;d++) bfr[kk][at].u[d] = pack2(v[2*d], v[2*d+1]);
    }
  }
  const unsigned short* Qb = QTf + (size_t)b*QTF_B;
  int mt = rem*4 + w;
  int nb = (mt>>1)*512 + (mt&1)*16 + lq;        // A lane row = lq
  f32x4 acc[4];
  #pragma unroll
  for (int at=0;at<4;at++) acc[at] = (f32x4){0.f,0.f,0.f,0.f};
  #pragma unroll
  for (int kk=0;kk<3;kk++){
    U8 af;
    #pragma unroll
    for (int d=0;d<4;d++){
      int j0 = kk*32 + quad*8 + 2*d;
      int j1 = j0 + 1;
      unsigned u0 = (j0 < QC) ? (unsigned)Qb[(j0>>4)*QTF_C + (j0&15)*32 + nb] : 0u;
      unsigned u1 = (j1 < QC) ? (unsigned)Qb[(j1>>4)*QTF_C + (j1&15)*32 + nb] : 0u;
      af.u[d] = u0 | (u1 << 16);
    }
    #pragma unroll
    for (int at=0;at<4;at++)
      acc[at] = __builtin_amdgcn_mfma_f32_16x16x32_bf16(af.v, bfr[kk][at].v, acc[at], 0, 0, 0);
  }
  float le = 0.f;
  #pragma unroll
  for (int r=0;r<4;r++){
    float s = 0.f;
    #pragma unroll
    for (int at=0;at<4;at++) s = fmaf(acc[at][r], acc[at][r], s);
    s += __shfl_xor(s, 1, 64);
    s += __shfl_xor(s, 2, 64);
    s += __shfl_xor(s, 4, 64);
    s += __shfl_xor(s, 8, 64);
    if (lq == 0){
      float o = s * (1.f/A_);
      ol[(size_t)b*NN + mt*16 + quad*4 + r] = o;
      le += expf(o);
    }
  }
  le += __shfl_down(le, 32, 64);
  le += __shfl_down(le, 16, 64);
  if (l == 0) wsum[w] = le;
  __syncthreads();
  if (tid == 0) atomicAdd(&esum[b], wsum[0]+wsum[1]+wsum[2]+wsum[3]);
}

// ---------------- k_fin ----------------
__global__ void k_fin(const float* ol, const float* esum, const int* flag, void* out){
  int idx = blockIdx.x*256 + threadIdx.x;
  if (idx < B_*NN){
    int b = idx / NN;
    float v = ol[idx] - logf(esum[b]);
    if (*flag) ((float*)out)[idx] = v;
    else       ((bf16*)out)[idx]  = __float2bfloat16(v);
  }
}

extern "C" void kernel_launch(void* const* d_in, const int* in_sizes, int n_in,
                              void* d_out, int out_size, void* d_ws, size_t ws_size,
                              hipStream_t stream) {
  (void)in_sizes; (void)n_in; (void)out_size; (void)ws_size;
  const int* ops  = (const int*)d_in[17];
  const int* args = (const int*)d_in[18];
  const int* gtc  = (const int*)d_in[19];
  const int* gta  = (const int*)d_in[20];

  float* ws = (float*)d_ws;
  int* flag = (int*)ws;
  float* W  = ws + 16;

  const float* meta_init  = W + 589824;
  const float* att_init   = W + 589888;
  const float* aw1        = W + 589952;
  const float* ab1        = W + 622720;
  const float* aw2        = W + 622976;
  const float* ab2        = W + 639360;
  const float* mw1        = W + 639424;
  const float* mb1        = W + 672192;
  const float* mw2        = W + 672448;
  const float* mb2        = W + 688832;

  constexpr size_t OFF_OBJIN   = 16 + TOT_IN;            // 688912
  constexpr size_t OFF_OBJOUT  = OFF_OBJIN  + 65536;
  constexpr size_t OFF_METAALL = OFF_OBJOUT + 65536;
  constexpr size_t OFF_METAH   = OFF_METAALL + 6144;
  constexpr size_t OFF_QSUM    = OFF_METAH  + 24576;
  constexpr size_t OFF_ESUM    = OFF_QSUM   + 640;
  constexpr size_t OFF_UT0     = OFF_ESUM   + 16;
  constexpr size_t OFF_UT1     = OFF_UT0    + 491520;
  constexpr size_t OFF_CM      = OFF_UT1    + 491520;
  constexpr size_t OFF_OL      = OFF_CM     + 40960;
  constexpr size_t OFF_QTF     = OFF_OL     + 33792;
  constexpr size_t OFF_AOPTC   = OFF_QTF    + 1351680;
  constexpr size_t OFF_AOPTO   = OFF_AOPTC  + 524288;
  constexpr size_t OFF_AWF     = OFF_AOPTO  + 131072;
  constexpr size_t OFF_TB      = OFF_AWF    + 8192;      // 8 partials x 983040 dwords
  // end = OFF_TB + 7864320 = 11,788,704 floats ~= 47.2 MB (ws is 256 MiB)

  float* objIn   = ws + OFF_OBJIN;
  float* objOut  = ws + OFF_OBJOUT;
  float* metaAll = ws + OFF_METAALL;
  float* metaH   = ws + OFF_METAH;
  float* qsum    = ws + OFF_QSUM;
  float* esum    = ws + OFF_ESUM;
  float* Ut0     = ws + OFF_UT0;
  float* Ut1     = ws + OFF_UT1;
  float* Cm      = ws + OFF_CM;
  float* ol      = ws + OFF_OL;
  unsigned short* QTf    = (unsigned short*)(ws + OFF_QTF);
  unsigned short* AoptC  = (unsigned short*)(ws + OFF_AOPTC);
  unsigned short* AoptO  = (unsigned short*)(ws + OFF_AOPTO);
  unsigned short* awFrag = (unsigned short*)(ws + OFF_AWF);
  unsigned* TB           = (unsigned*)(ws + OFF_TB);

  Ptr16 ps;
  const int src_idx[16] = {0,1,2,3,4,5,6,8,9,10,11,12,13,14,15,16};
  for (int i=0;i<16;i++) ps.p[i] = d_in[src_idx[i]];

  k_prep<<<482, 256, 0, stream>>>(ps, flag, W, awFrag, gtc, gta, objIn, objOut, qsum);
  k_mid <<<224, 256, 0, stream>>>(ps, flag, meta_init, mw1, mb1, mw2, mb2,
                                  aw1, ab1, ops, args, objIn, objOut, awFrag,
                                  metaAll, metaH, QTf, qsum, AoptC, AoptO);
  k_T   <<<B_*LP*4*8, 64, 0, stream>>>(AoptC, AoptO, QTf, metaH, ops, TB);
  k_U   <<<B_*LP*2, 256, 0, stream>>>(TB, aw2, ab2, qsum, ops, Ut0, Ut1);
  k_rec <<<B_, 256, 0, stream>>>(Ut0, Ut1, metaAll, ops, att_init, Cm);
  k_out <<<B_*66, 256, 0, stream>>>(QTf, Cm, ol, esum);
  k_fin <<<(B_*NN + 255)/256, 256, 0, stream>>>(ol, esum, flag, d_out);
}

// Round 12
// 216.429 us; speedup vs baseline: 1.0624x; 1.0033x over previous
//
#include <hip/hip_runtime.h>
#include <hip/hip_bf16.h>

typedef __hip_bfloat16 bf16;
typedef float f32x4 __attribute__((ext_vector_type(4)));
typedef short s16x8 __attribute__((ext_vector_type(8)));

#define B_    8
#define LP    12
#define NC    4096
#define NO    128
#define NAPO  8
#define NN    4224
#define E_    64
#define A_    64
#define H_    256
#define QC    80
#define PROJ0 65
#define NCHUNK 17

#define TOT_IN 688896
#define QTF_C  67584     // 132*512 shorts per (b,c) group
#define QTF_B  337920    // 5*QTF_C per batch
#define TB_P   983040    // dwords per kh-partial: 96*4*2560

struct Ptr16 { const void* p[16]; };
union U8 { s16x8 v; unsigned u[4]; };

__device__ __forceinline__ float b2f(bf16 x){ return __bfloat162float(x); }
__device__ __forceinline__ float bs2f(unsigned short s){
  union { unsigned u; float f; } x; x.u = ((unsigned)s) << 16; return x.f;
}
__device__ __forceinline__ unsigned short f2bs(float f){
  bf16 h = __float2bfloat16(f);
  union { bf16 h; unsigned short s; } x; x.h = h; return x.s;
}
__device__ __forceinline__ unsigned pack2(float a, float b){
  return (unsigned)f2bs(a) | ((unsigned)f2bs(b) << 16);
}
__device__ __forceinline__ float lo16f(unsigned w){
  union { unsigned u; float f; } x; x.u = w << 16; return x.f;
}
__device__ __forceinline__ float hi16f(unsigned w){
  union { unsigned u; float f; } x; x.u = w & 0xffff0000u; return x.f;
}
__device__ __forceinline__ float rdval(const void* p, size_t i, int fl){
  return fl ? ((const float*)p)[i] : bs2f(((const unsigned short*)p)[i]);
}

// ---------------- k_prep v4: concept tensors NOT converted; obj gather branch-hoisted ----------------
__global__ void k_prep(Ptr16 ps, int* flag, float* dst,
                       unsigned short* awFrag,
                       const int* gtc, const int* gta,
                       float* objIn, float* objOut, float* qsum_esum){
  int tid = threadIdx.x;
  // wave-local dtype detect: probe concept_embIn even half-words; fp32 garbage -> ~46% exp>=137
  const unsigned short* u = (const unsigned short*)ps.p[4];
  int hit = (((u[tid*16] >> 7) & 0xFF) >= 137) ? 1 : 0;
  unsigned long long m = __ballot(hit);
  int fl = (m != 0ULL) ? 1 : 0;
  int mb = blockIdx.x;
  if (mb < 161){
    int qi = mb*256 + tid;
    if (qi >= 41152) return;
    int idx = (qi < 16384) ? qi*4 : qi*4 + 524288;   // skip concept tensors [65536,589824)
    constexpr int cum[17] = {0,16384,32768,49152,65536,327680,589824,589888,589952,
                             622720,622976,639360,639424,672192,672448,688832,688896};
    int t = 0;
    #pragma unroll
    for (int i=1;i<16;i++) if (idx >= cum[i]) t = i;
    int off = idx - cum[t];
    float4 v;
    if (fl){
      v = *(const float4*)((const float*)ps.p[t] + off);
    } else {
      uint2 sv = *(const uint2*)((const unsigned short*)ps.p[t] + off);
      v.x = lo16f(sv.x); v.y = hi16f(sv.x);
      v.z = lo16f(sv.y); v.w = hi16f(sv.y);
    }
    *(float4*)(dst + idx) = v;
  } else if (mb < 225){
    int idx = (mb-161)*256 + tid;               // < 16384
    int j = idx & 7;
    int lane = (idx >> 3) & 63;
    int mm = (idx >> 9) & 15;
    int kc = idx >> 13;
    int e = kc*32 + (lane>>4)*8 + j;
    int h = mm*16 + (lane&15);
    awFrag[idx] = f2bs(rdval(ps.p[8], (size_t)e*H_ + h, fl));
  } else if (mb < 481){
    int idx = (mb-225)*256 + tid;               // < 65536
    int e = idx & 63; int bo = idx >> 6;
    int cls = gtc[bo];
    const int* ga = gta + bo*NAPO;
    float vi, vo;
    if (fl){
      const float* p0 = (const float*)ps.p[0];
      const float* p1 = (const float*)ps.p[1];
      const float* p2 = (const float*)ps.p[2];
      const float* p3 = (const float*)ps.p[3];
      vi = p0[(size_t)cls*E_ + e];
      vo = p1[(size_t)cls*E_ + e];
      #pragma unroll
      for (int j=0;j<NAPO;j++){
        int at = ga[j];
        vi += p2[(size_t)at*E_ + e];
        vo += p3[(size_t)at*E_ + e];
      }
    } else {
      const unsigned short* p0 = (const unsigned short*)ps.p[0];
      const unsigned short* p1 = (const unsigned short*)ps.p[1];
      const unsigned short* p2 = (const unsigned short*)ps.p[2];
      const unsigned short* p3 = (const unsigned short*)ps.p[3];
      vi = bs2f(p0[(size_t)cls*E_ + e]);
      vo = bs2f(p1[(size_t)cls*E_ + e]);
      #pragma unroll
      for (int j=0;j<NAPO;j++){
        int at = ga[j];
        vi += bs2f(p2[(size_t)at*E_ + e]);
        vo += bs2f(p3[(size_t)at*E_ + e]);
      }
    }
    objIn[idx] = vi; objOut[idx] = vo;
  } else {
    if (tid < 656) qsum_esum[tid] = 0.f;        // qsum(640) + esum(16)
    if (tid == 0) *flag = fl;
  }
}

// ================ k_mid: meta(8) | QTf+qsum(136) | baseT->Aopt(80) ================
// mid_meta v3: op-skip + raw concept reads (argx only; weights are converted).
__device__ __forceinline__ void mid_meta(char* smem, int b, int fl, const void* coRaw,
                       const float* meta_init,
                       const float* mw1, const float* mb1, const float* mw2, const float* mb2,
                       const float* aw1, const float* ab1,
                       const int* ops, const int* args,
                       float* metaAll, float* metaH){
  unsigned* mw1p = (unsigned*)smem;               // 64*256 = 65536 B
  unsigned* mw2p = (unsigned*)(smem + 65536);     // 128*64 = 32768 B
  unsigned* aw1p = (unsigned*)(smem + 98304);     // 32*256 = 32768 B
  float* meta_s  = (float*)(smem + 131072);
  float* argx    = (float*)(smem + 131328);
  float* hid     = (float*)(smem + 131584);
  float* part    = (float*)(smem + 132608);
  int tid = threadIdx.x;

  for (int i=tid; i<64*256; i+=256){
    int j2 = i >> 8, t = i & 255;
    mw1p[i] = pack2(mw1[(2*j2)*H_ + t], mw1[(2*j2+1)*H_ + t]);
  }
  for (int i=tid; i<128*64; i+=256){
    int h2 = i >> 6, a = i & 63;
    mw2p[i] = pack2(mw2[(2*h2)*A_ + a], mw2[(2*h2+1)*A_ + a]);
  }
  for (int i=tid; i<32*256; i+=256){
    int a2 = i >> 8, t = i & 255;
    aw1p[i] = pack2(aw1[(E_+2*a2)*H_ + t], aw1[(E_+2*a2+1)*H_ + t]);
  }
  float r_mb1 = mb1[tid];
  float r_ab1 = ab1[tid];
  float r_mb2 = (tid < A_) ? mb2[tid] : 0.f;
  if (tid < A_) meta_s[tid] = meta_init[tid];
  __syncthreads();

  // initial metaH (from initial meta)
  float mh = r_ab1;
  for (int a2=0;a2<32;a2++){
    unsigned w = aw1p[a2*256 + tid];
    float2 mp = *(const float2*)&meta_s[2*a2];
    mh = fmaf(mp.x, lo16f(w), mh);
    mh = fmaf(mp.y, hi16f(w), mh);
  }

  for (int t=0;t<LP;t++){
    int op  = ops[b*LP + t];
    if (op == 0){
      int arg = args[b*LP + t];
      if (tid >= 64 && tid < 128) argx[tid-64] = rdval(coRaw, (size_t)arg*E_ + (tid-64), fl);
      __syncthreads();
      float acc = r_mb1;
      for (int j2=0;j2<32;j2++){
        unsigned w = mw1p[j2*256 + tid];
        float2 xp = *(const float2*)&meta_s[2*j2];
        acc = fmaf(xp.x, lo16f(w), acc);
        acc = fmaf(xp.y, hi16f(w), acc);
      }
      for (int j2=0;j2<32;j2++){
        unsigned w = mw1p[(32+j2)*256 + tid];
        float2 xp = *(const float2*)&argx[2*j2];
        acc = fmaf(xp.x, lo16f(w), acc);
        acc = fmaf(xp.y, hi16f(w), acc);
      }
      hid[tid] = fmaxf(acc, 0.f);
      __syncthreads();
      int wv_ = tid >> 6, l = tid & 63;
      float acc2 = 0.f;
      for (int h2 = wv_*32; h2 < wv_*32+32; h2++){
        unsigned w = mw2p[h2*64 + l];
        float2 hp = *(const float2*)&hid[2*h2];
        acc2 = fmaf(hp.x, lo16f(w), acc2);
        acc2 = fmaf(hp.y, hi16f(w), acc2);
      }
      part[wv_*64 + l] = acc2;
      __syncthreads();
      if (tid < A_){
        float s = part[tid] + part[64+tid] + part[128+tid] + part[192+tid] + r_mb2;
        meta_s[tid] = s;
      }
      __syncthreads();
      mh = r_ab1;
      for (int a2=0;a2<32;a2++){
        unsigned w = aw1p[a2*256 + tid];
        float2 mp = *(const float2*)&meta_s[2*a2];
        mh = fmaf(mp.x, lo16f(w), mh);
        mh = fmaf(mp.y, hi16f(w), mh);
      }
    }
    if (tid < A_) metaAll[(b*LP+t)*A_ + tid] = meta_s[tid];
    metaH[(b*LP+t)*H_ + tid] = mh;
  }
}

// mid_qt v5: vectorized global staging (s16x8/float4) + column-sum reduction + proj-skip
__device__ __forceinline__ void mid_qt(char* smem, int idx, int fl,
                       const void* ciRaw, const void* coRaw, const int* args,
                       const float* objIn, const float* objOut, const int* ops,
                       unsigned short* QTf, float* qsum){
  float* tile = (float*)smem;                  // 256*65*4 = 66560 B
  float* argv = (float*)(smem + 66560);        // 3072 B
  float* qs   = (float*)(smem + 69632);        // 320 B
  float* colp = (float*)(smem + 69952);        // 1024 B
  int b = idx / NCHUNK, chunk = idx % NCHUNK;
  int tid = threadIdx.x;
  int rows = (chunk < 16) ? 256 : 128;
  int n0 = chunk*256;
  int n = n0 + tid;
  bool valid = (tid < rows);
  if (tid < 80) qs[tid] = 0.f;
  int opsv[LP];
  #pragma unroll
  for (int t=0;t<LP;t++) opsv[t] = ops[b*LP + t];
  unsigned short* Qb = QTf + (size_t)b*QTF_B + ((n>>5)*512 + (n&31));
  {
    int tot = rows*64;
    if (chunk < 16){
      if (fl){
        const float* src = (const float*)ciRaw + (size_t)n0*E_;
        for (int i=tid*4; i<tot; i+=1024){
          float4 v = *(const float4*)(src + i);
          float* d = &tile[(i>>6)*65 + (i&63)];
          d[0]=v.x; d[1]=v.y; d[2]=v.z; d[3]=v.w;
        }
      } else {
        const unsigned short* src = (const unsigned short*)ciRaw + (size_t)n0*E_;
        for (int i=tid*8; i<tot; i+=2048){
          U8 a; a.v = *(const s16x8*)(src + i);
          float* d = &tile[(i>>6)*65 + (i&63)];
          d[0]=lo16f(a.u[0]); d[1]=hi16f(a.u[0]);
          d[2]=lo16f(a.u[1]); d[3]=hi16f(a.u[1]);
          d[4]=lo16f(a.u[2]); d[5]=hi16f(a.u[2]);
          d[6]=lo16f(a.u[3]); d[7]=hi16f(a.u[3]);
        }
      }
    } else {
      const float* src = objIn + (size_t)b*NO*E_;
      for (int i=tid*4; i<tot; i+=1024){
        float4 v = *(const float4*)(src + i);
        float* d = &tile[(i>>6)*65 + (i&63)];
        d[0]=v.x; d[1]=v.y; d[2]=v.z; d[3]=v.w;
      }
    }
  }
  __syncthreads();
  if (valid){
    Qb[0] = 0x3F80;
    Qb[4*QTF_C + 13*32] = 0;
    Qb[4*QTF_C + 14*32] = 0;
    Qb[4*QTF_C + 15*32] = 0;
    for (int e=0;e<64;e++){
      int qc = 1+e;
      Qb[(qc>>4)*QTF_C + (qc&15)*32] = f2bs(tile[tid*65 + e]);
    }
  }
  // column sums via row-groups (replaces 64 LDS atomics/thread)
  {
    int col = tid & 63, rg = tid >> 6;
    float s = 0.f;
    int r0 = rg*64; int r1 = r0+64; if (r1 > rows) r1 = rows;
    for (int r=r0; r<r1; r++) s += tile[r*65 + col];
    colp[rg*64 + col] = s;
  }
  __syncthreads();
  if (tid < 64) qs[1+tid] = colp[tid] + colp[64+tid] + colp[128+tid] + colp[192+tid];
  if (fl){
    const float* co = (const float*)coRaw;
    for (int i=tid;i<LP*E_;i+=256) argv[i] = co[(size_t)args[b*LP + (i>>6)]*E_ + (i&63)];
  } else {
    const unsigned short* co = (const unsigned short*)coRaw;
    for (int i=tid;i<LP*E_;i+=256) argv[i] = bs2f(co[(size_t)args[b*LP + (i>>6)]*E_ + (i&63)]);
  }
  {
    int tot = rows*64;
    if (chunk < 16){
      if (fl){
        const float* src = (const float*)coRaw + (size_t)n0*E_;
        for (int i=tid*4; i<tot; i+=1024){
          float4 v = *(const float4*)(src + i);
          float* d = &tile[(i>>6)*65 + (i&63)];
          d[0]=v.x; d[1]=v.y; d[2]=v.z; d[3]=v.w;
        }
      } else {
        const unsigned short* src = (const unsigned short*)coRaw + (size_t)n0*E_;
        for (int i=tid*8; i<tot; i+=2048){
          U8 a; a.v = *(const s16x8*)(src + i);
          float* d = &tile[(i>>6)*65 + (i&63)];
          d[0]=lo16f(a.u[0]); d[1]=hi16f(a.u[0]);
          d[2]=lo16f(a.u[1]); d[3]=hi16f(a.u[1]);
          d[4]=lo16f(a.u[2]); d[5]=hi16f(a.u[2]);
          d[6]=lo16f(a.u[3]); d[7]=hi16f(a.u[3]);
        }
      }
    } else {
      const float* src = objOut + (size_t)b*NO*E_;
      for (int i=tid*4; i<tot; i+=1024){
        float4 v = *(const float4*)(src + i);
        float* d = &tile[(i>>6)*65 + (i&63)];
        d[0]=v.x; d[1]=v.y; d[2]=v.z; d[3]=v.w;
      }
    }
  }
  __syncthreads();
  float dots[LP];
  #pragma unroll
  for (int t=0;t<LP;t++) dots[t] = 0.f;
  for (int e=0;e<64;e++){
    float o = tile[tid*65 + e];
    #pragma unroll
    for (int t=0;t<LP;t++) dots[t] += o*argv[t*64+e];
  }
  #pragma unroll
  for (int t=0;t<LP;t++){
    int opt = opsv[t];
    float v = (valid && opt == 1) ? dots[t]*(1.f/E_) : 0.f;
    if (valid){
      int qc = PROJ0+t;
      Qb[(qc>>4)*QTF_C + (qc&15)*32] = f2bs(v);
    }
    if (opt == 1){
      float r = v;
      #pragma unroll
      for (int off=32; off>0; off>>=1) r += __shfl_down(r, off, 64);
      if ((tid & 63) == 0) atomicAdd(&qs[PROJ0+t], r);
    }
  }
  __syncthreads();
  if (tid < 80) atomicAdd(&qsum[b*QC + tid], qs[tid]);
  if (chunk == 0 && tid == 0) atomicAdd(&qsum[b*QC], (float)NN);
}

// mid_base v2: raw conceptOut reads (bf16 path loads s16x8 directly)
__device__ __forceinline__ void mid_base(int blk, int fl, const void* coRaw,
                       const float* objOut,
                       const unsigned short* awFrag,
                       unsigned short* AoptC, unsigned short* AoptO){
  int n0 = blk * 64;
  int tid = threadIdx.x;
  int w = tid >> 6, l = tid & 63, quad = l >> 4, lq = l & 15;
  int n = n0 + w*16 + lq;
  f32x4 acc[16];
  #pragma unroll
  for (int m=0;m<16;m++) acc[m] = (f32x4){0.f,0.f,0.f,0.f};
  #pragma unroll
  for (int kc=0;kc<2;kc++){
    s16x8 bfr;
    size_t eoff = (size_t)0 + kc*32 + quad*8;
    if (n < NC){
      if (fl){
        const float* src = (const float*)coRaw + (size_t)n*E_;
        #pragma unroll
        for (int j=0;j<8;j++) bfr[j] = (short)f2bs(src[eoff + j]);
      } else {
        bfr = *(const s16x8*)((const unsigned short*)coRaw + (size_t)n*E_ + eoff);
      }
    } else {
      const float* src = objOut + (size_t)(n-NC)*E_;
      #pragma unroll
      for (int j=0;j<8;j++) bfr[j] = (short)f2bs(src[eoff + j]);
    }
    const unsigned short* ap = awFrag + ((size_t)(kc*16)*64 + l)*8;
    #pragma unroll
    for (int m=0;m<16;m++){
      s16x8 af = *(const s16x8*)(ap + (size_t)m*64*8);
      acc[m] = __builtin_amdgcn_mfma_f32_16x16x32_bf16(af, bfr, acc[m], 0, 0, 0);
    }
  }
  int nl = n & 31;
  if (n < NC){
    int nch = n >> 5;
    #pragma unroll
    for (int m=0;m<16;m++){
      #pragma unroll
      for (int r=0;r<4;r++)
        AoptC[(size_t)(m*128 + nch)*512 + (quad*4+r)*32 + nl] = f2bs(acc[m][r]);
    }
  } else {
    int no = n - NC; int bb = no >> 7; int oc = (no & 127) >> 5;
    #pragma unroll
    for (int m=0;m<16;m++){
      #pragma unroll
      for (int r=0;r<4;r++)
        AoptO[(size_t)((bb*16 + m)*4 + oc)*512 + (quad*4+r)*32 + nl] = f2bs(acc[m][r]);
    }
  }
}

__global__ __launch_bounds__(256) void k_mid(
    Ptr16 ps, const int* flag,
    const float* meta_init, const float* mw1, const float* mb1, const float* mw2, const float* mb2,
    const float* aw1, const float* ab1, const int* ops, const int* args,
    const float* objIn, const float* objOut, const unsigned short* awFrag,
    float* metaAll, float* metaH, unsigned short* QTf, float* qsum,
    unsigned short* AoptC, unsigned short* AoptO){
  __shared__ __align__(16) char smem[133888];
  int fl = *flag;
  const void* ciRaw = ps.p[4];
  const void* coRaw = ps.p[5];
  int mb = blockIdx.x;
  if (mb < 8)
    mid_meta(smem, mb, fl, coRaw, meta_init, mw1, mb1, mw2, mb2, aw1, ab1, ops, args, metaAll, metaH);
  else if (mb < 144)
    mid_qt(smem, mb-8, fl, ciRaw, coRaw, args, objIn, objOut, ops, QTf, qsum);
  else
    mid_base(mb-144, fl, coRaw, objOut, awFrag, AoptC, AoptO);
}

// ---------------- k_T v7: single-wave blocks, kh 8-way K-split + op-skip ----------------
__global__ __launch_bounds__(64) void k_T(const unsigned short* AoptC, const unsigned short* AoptO,
                                          const unsigned short* QTf, const float* metaH,
                                          const int* ops, unsigned* TB){
  int bid = blockIdx.x;
  int kh = bid & 7; int ht = (bid >> 3) & 3; int bt = bid >> 5; int b = bt / LP;
  if (ops[bt] != 2) return;
  int l = threadIdx.x, quad = l >> 4, lq = l & 15;
  int off = lq*32 + quad*8;
  int start = (kh < 4) ? (kh*17) : (68 + (kh-4)*16);
  int count = (kh < 4) ? 17 : 16;
  float mh[4];
  #pragma unroll
  for (int s=0;s<4;s++) mh[s] = metaH[(size_t)bt*H_ + ht*64 + s*16 + lq];
  f32x4 acc[4][5];
  #pragma unroll
  for (int s=0;s<4;s++){
    #pragma unroll
    for (int c=0;c<5;c++) acc[s][c] = (f32x4){0.f,0.f,0.f,0.f};
  }
  const unsigned short* QTb = QTf + (size_t)b*QTF_B + off;
  const unsigned short* AC  = AoptC + (size_t)(ht*4)*65536 + off;       // 65536 = 128*512
  const unsigned short* AO  = AoptO + (size_t)(b*16 + ht*4)*2048 + off; // 2048 = 4*512
  for (int it=0; it<count; it++){
    int nchunk = start + it;
    U8 bfr[5];
    #pragma unroll
    for (int c=0;c<5;c++)
      bfr[c].v = *(const s16x8*)(QTb + (size_t)c*QTF_C + (size_t)nchunk*512);
    bool isC = (nchunk < 128);
    #pragma unroll
    for (int s=0;s<4;s++){
      U8 a;
      a.v = isC ? *(const s16x8*)(AC + (size_t)s*65536 + (size_t)nchunk*512)
                : *(const s16x8*)(AO + (size_t)s*2048 + (size_t)(nchunk-128)*512);
      float mhs = mh[s];
      U8 af;
      #pragma unroll
      for (int d=0;d<4;d++){
        unsigned wv = a.u[d];
        float lo = fmaxf(__uint_as_float(wv << 16) + mhs, 0.f);
        float hi = fmaxf(__uint_as_float(wv & 0xffff0000u) + mhs, 0.f);
        af.u[d] = __builtin_amdgcn_perm(__float_as_uint(hi), __float_as_uint(lo), 0x07060302u);
      }
      #pragma unroll
      for (int c=0;c<5;c++)
        acc[s][c] = __builtin_amdgcn_mfma_f32_16x16x32_bf16(af.v, bfr[c].v, acc[s][c], 0, 0, 0);
    }
  }
  unsigned* Tp = TB + (size_t)kh*TB_P + ((size_t)bt*4 + ht)*2560;
  #pragma unroll
  for (int s=0;s<4;s++){
    #pragma unroll
    for (int c=0;c<5;c++){
      uint2 v;
      v.x = pack2(acc[s][c][0], acc[s][c][1]);
      v.y = pack2(acc[s][c][2], acc[s][c][3]);
      *(uint2*)(Tp + (s*5+c)*128 + l*2) = v;
    }
  }
}

// ---------------- k_U v4: K-split x2 + op-skip ----------------
__global__ __launch_bounds__(256) void k_U(const unsigned* TB,
                                           const float* w2, const float* b2v,
                                           const float* qsum, const int* ops,
                                           float* Ut0, float* Ut1){
  __shared__ float Wt[128*64];
  __shared__ float Tt[128*81];
  int bid = blockIdx.x;
  int kq = bid & 1; int bt = bid >> 1; int b = bt / LP;
  if (ops[bt] != 2) return;
  int tid = threadIdx.x;
  for (int i=tid; i<8192; i+=256){
    int hl = i >> 6, e = i & 63;
    Wt[i] = w2[(kq*128 + hl)*E_ + e];
  }
  #pragma unroll
  for (int half=0; half<2; half++){
    const unsigned* base = TB + ((size_t)bt*4 + kq*2 + half)*2560;
    for (int i2=tid; i2<2560; i2+=256){
      float lo = 0.f, hi = 0.f;
      #pragma unroll
      for (int p=0;p<8;p++){
        unsigned w = base[(size_t)p*TB_P + i2];
        lo += lo16f(w); hi += hi16f(w);
      }
      int idx = 2*i2;
      int sc = idx >> 8; int ll = (idx >> 2) & 63; int r = idx & 3;
      int s = sc/5, c = sc - s*5;
      int hl = half*64 + s*16 + ((ll>>4)<<2) + r;
      int qc = c*16 + (ll&15);
      Tt[hl*81 + qc]     = lo;
      Tt[(hl+1)*81 + qc] = hi;
    }
  }
  __syncthreads();
  int el = tid & 15, ql = tid >> 4;
  float acc[4][5];
  #pragma unroll
  for (int i=0;i<4;i++){
    #pragma unroll
    for (int j=0;j<5;j++) acc[i][j]=0.f;
  }
  #pragma unroll 4
  for (int kk=0; kk<128; kk++){
    float4 wv = *(const float4*)&Wt[kk*64 + el*4];
    float ww[4] = {wv.x, wv.y, wv.z, wv.w};
    const float* tp = &Tt[kk*81 + ql*5];
    #pragma unroll
    for (int j=0;j<5;j++){
      float tv = tp[j];
      #pragma unroll
      for (int i=0;i<4;i++) acc[i][j] = fmaf(ww[i], tv, acc[i][j]);
    }
  }
  const float invN = 1.f/NN;
  float* Up = (kq ? Ut1 : Ut0) + (size_t)bt*5120;
  if (kq == 0){
    float be[4], qv[5];
    #pragma unroll
    for (int i=0;i<4;i++) be[i] = b2v[el*4+i];
    #pragma unroll
    for (int j=0;j<5;j++) qv[j] = qsum[b*QC + ql*5+j];
    #pragma unroll
    for (int i=0;i<4;i++){
      #pragma unroll
      for (int j=0;j<5;j++)
        Up[(el*4+i)*QC + ql*5+j] = (acc[i][j] + be[i]*qv[j]) * invN;
    }
  } else {
    #pragma unroll
    for (int i=0;i<4;i++){
      #pragma unroll
      for (int j=0;j<5;j++)
        Up[(el*4+i)*QC + ql*5+j] = acc[i][j] * invN;
    }
  }
}

// ---------------- k_rec v6: op-skip + gated Ul prefetch ----------------
__global__ __launch_bounds__(256) void k_rec(const float* Ut0, const float* Ut1, const float* metaAll,
                                             const int* ops, const float* att_init, float* Cm){
  __shared__ float C[QC*65];
  __shared__ float Ul[2][64*81];
  int b = blockIdx.x, tid = threadIdx.x;
  int w = tid >> 6, l = tid & 63, quad = l >> 4, lq = l & 15;
  for (int i=tid;i<QC*65;i+=256) C[i] = 0.f;
  if (tid < A_) C[tid] = att_init[tid];
  if (ops[b*LP] == 2){
    const float* U0 = Ut0 + (size_t)(b*LP)*5120;
    const float* U1 = Ut1 + (size_t)(b*LP)*5120;
    #pragma unroll
    for (int k=0;k<5;k++){
      int i = tid*4 + k*1024;
      float4 v0 = *(const float4*)&U0[i];
      float4 v1 = *(const float4*)&U1[i];
      int r = i/80, c = i%80;
      Ul[0][r*81+c]   = v0.x+v1.x; Ul[0][r*81+c+1] = v0.y+v1.y;
      Ul[0][r*81+c+2] = v0.z+v1.z; Ul[0][r*81+c+3] = v0.w+v1.w;
    }
  }
  __syncthreads();
  for (int t=0;t<LP;t++){
    int opn = (t < LP-1) ? ops[b*LP + t + 1] : 0;
    float4 rv0[5], rv1[5];
    if (opn == 2){
      const float* U0 = Ut0 + (size_t)(b*LP+t+1)*5120;
      const float* U1 = Ut1 + (size_t)(b*LP+t+1)*5120;
      #pragma unroll
      for (int k=0;k<5;k++){
        rv0[k] = *(const float4*)&U0[tid*4 + k*1024];
        rv1[k] = *(const float4*)&U1[tid*4 + k*1024];
      }
    }
    int op = ops[b*LP + t];
    f32x4 acc[4];
    if (op == 2){
      const float* Uc = Ul[t&1];
      U8 af[3][4];
      #pragma unroll
      for (int k0t=0;k0t<3;k0t++){
        #pragma unroll
        for (int s=0;s<4;s++){
          int e = s*16 + lq;
          int qb = k0t*32 + quad*8;
          float v[8];
          #pragma unroll
          for (int j=0;j<8;j++){
            int qc = qb + j;
            v[j] = (qc < QC) ? Uc[e*81 + qc] : 0.f;
          }
          #pragma unroll
          for (int d=0;d<4;d++) af[k0t][s].u[d] = pack2(v[2*d], v[2*d+1]);
        }
      }
      U8 bf[3];
      #pragma unroll
      for (int k0t=0;k0t<3;k0t++){
        int kb = k0t*32 + quad*8;
        float v[8];
        #pragma unroll
        for (int j=0;j<8;j++){
          int k = kb + j;
          v[j] = (k < QC) ? C[k*65 + w*16 + lq] : 0.f;
        }
        #pragma unroll
        for (int d=0;d<4;d++) bf[k0t].u[d] = pack2(v[2*d], v[2*d+1]);
      }
      #pragma unroll
      for (int s=0;s<4;s++){
        acc[s] = (f32x4){0.f,0.f,0.f,0.f};
        #pragma unroll
        for (int k0t=0;k0t<3;k0t++)
          acc[s] = __builtin_amdgcn_mfma_f32_16x16x32_bf16(af[k0t][s].v, bf[k0t].v, acc[s], 0, 0, 0);
      }
    }
    __syncthreads();
    if (op == 2){
      #pragma unroll
      for (int s=0;s<4;s++){
        #pragma unroll
        for (int r=0;r<4;r++){
          int e = s*16 + quad*4 + r;
          C[(1+e)*65 + w*16 + lq] += acc[s][r];
        }
      }
    } else if (op == 1){
      if (tid < A_) C[(PROJ0+t)*65 + tid] += metaAll[(b*LP+t)*A_ + tid];
    }
    if (opn == 2){
      float* Un = Ul[(t+1)&1];
      #pragma unroll
      for (int k=0;k<5;k++){
        int i = tid*4 + k*1024;
        int r = i/80, c = i%80;
        Un[r*81+c]   = rv0[k].x+rv1[k].x; Un[r*81+c+1] = rv0[k].y+rv1[k].y;
        Un[r*81+c+2] = rv0[k].z+rv1[k].z; Un[r*81+c+3] = rv0[k].w+rv1[k].w;
      }
    }
    __syncthreads();
  }
  for (int i=tid;i<QC*A_;i+=256) Cm[b*QC*A_ + i] = C[(i>>6)*65 + (i&63)];
}

// ---------------- k_out v3: MFMA, wide grid ----------------
__global__ __launch_bounds__(256) void k_out(const unsigned short* QTf, const float* Cm,
                                             float* ol, float* esum){
  __shared__ float Cpad[QC*65];
  __shared__ float wsum[4];
  int b = blockIdx.x / 66, rem = blockIdx.x % 66;
  int tid = threadIdx.x;
  int w = tid >> 6, l = tid & 63, quad = l >> 4, lq = l & 15;
  for (int i=tid; i<QC*A_; i+=256) Cpad[(i>>6)*65 + (i&63)] = Cm[b*QC*A_ + i];
  __syncthreads();
  U8 bfr[3][4];
  #pragma unroll
  for (int kk=0;kk<3;kk++){
    #pragma unroll
    for (int at=0;at<4;at++){
      float v[8];
      #pragma unroll
      for (int jj=0;jj<8;jj++){
        int j = kk*32 + quad*8 + jj;
        v[jj] = (j < QC) ? Cpad[j*65 + at*16 + lq] : 0.f;
      }
      #pragma unroll
      for (int d=0;d<4;d++) bfr[kk][at].u[d] = pack2(v[2*d], v[2*d+1]);
    }
  }
  const unsigned short* Qb = QTf + (size_t)b*QTF_B;
  int mt = rem*4 + w;
  int nb = (mt>>1)*512 + (mt&1)*16 + lq;        // A lane row = lq
  f32x4 acc[4];
  #pragma unroll
  for (int at=0;at<4;at++) acc[at] = (f32x4){0.f,0.f,0.f,0.f};
  #pragma unroll
  for (int kk=0;kk<3;kk++){
    U8 af;
    #pragma unroll
    for (int d=0;d<4;d++){
      int j0 = kk*32 + quad*8 + 2*d;
      int j1 = j0 + 1;
      unsigned u0 = (j0 < QC) ? (unsigned)Qb[(j0>>4)*QTF_C + (j0&15)*32 + nb] : 0u;
      unsigned u1 = (j1 < QC) ? (unsigned)Qb[(j1>>4)*QTF_C + (j1&15)*32 + nb] : 0u;
      af.u[d] = u0 | (u1 << 16);
    }
    #pragma unroll
    for (int at=0;at<4;at++)
      acc[at] = __builtin_amdgcn_mfma_f32_16x16x32_bf16(af.v, bfr[kk][at].v, acc[at], 0, 0, 0);
  }
  float le = 0.f;
  #pragma unroll
  for (int r=0;r<4;r++){
    float s = 0.f;
    #pragma unroll
    for (int at=0;at<4;at++) s = fmaf(acc[at][r], acc[at][r], s);
    s += __shfl_xor(s, 1, 64);
    s += __shfl_xor(s, 2, 64);
    s += __shfl_xor(s, 4, 64);
    s += __shfl_xor(s, 8, 64);
    if (lq == 0){
      float o = s * (1.f/A_);
      ol[(size_t)b*NN + mt*16 + quad*4 + r] = o;
      le += expf(o);
    }
  }
  le += __shfl_down(le, 32, 64);
  le += __shfl_down(le, 16, 64);
  if (l == 0) wsum[w] = le;
  __syncthreads();
  if (tid == 0) atomicAdd(&esum[b], wsum[0]+wsum[1]+wsum[2]+wsum[3]);
}

// ---------------- k_fin ----------------
__global__ void k_fin(const float* ol, const float* esum, const int* flag, void* out){
  int idx = blockIdx.x*256 + threadIdx.x;
  if (idx < B_*NN){
    int b = idx / NN;
    float v = ol[idx] - logf(esum[b]);
    if (*flag) ((float*)out)[idx] = v;
    else       ((bf16*)out)[idx]  = __float2bfloat16(v);
  }
}

extern "C" void kernel_launch(void* const* d_in, const int* in_sizes, int n_in,
                              void* d_out, int out_size, void* d_ws, size_t ws_size,
                              hipStream_t stream) {
  (void)in_sizes; (void)n_in; (void)out_size; (void)ws_size;
  const int* ops  = (const int*)d_in[17];
  const int* args = (const int*)d_in[18];
  const int* gtc  = (const int*)d_in[19];
  const int* gta  = (const int*)d_in[20];

  float* ws = (float*)d_ws;
  int* flag = (int*)ws;
  float* W  = ws + 16;

  const float* meta_init  = W + 589824;
  const float* att_init   = W + 589888;
  const float* aw1        = W + 589952;
  const float* ab1        = W + 622720;
  const float* aw2        = W + 622976;
  const float* ab2        = W + 639360;
  const float* mw1        = W + 639424;
  const float* mb1        = W + 672192;
  const float* mw2        = W + 672448;
  const float* mb2        = W + 688832;

  constexpr size_t OFF_OBJIN   = 16 + TOT_IN;            // 688912
  constexpr size_t OFF_OBJOUT  = OFF_OBJIN  + 65536;
  constexpr size_t OFF_METAALL = OFF_OBJOUT + 65536;
  constexpr size_t OFF_METAH   = OFF_METAALL + 6144;
  constexpr size_t OFF_QSUM    = OFF_METAH  + 24576;
  constexpr size_t OFF_ESUM    = OFF_QSUM   + 640;
  constexpr size_t OFF_UT0     = OFF_ESUM   + 16;
  constexpr size_t OFF_UT1     = OFF_UT0    + 491520;
  constexpr size_t OFF_CM      = OFF_UT1    + 491520;
  constexpr size_t OFF_OL      = OFF_CM     + 40960;
  constexpr size_t OFF_QTF     = OFF_OL     + 33792;
  constexpr size_t OFF_AOPTC   = OFF_QTF    + 1351680;
  constexpr size_t OFF_AOPTO   = OFF_AOPTC  + 524288;
  constexpr size_t OFF_AWF     = OFF_AOPTO  + 131072;
  constexpr size_t OFF_TB      = OFF_AWF    + 8192;      // 8 partials x 983040 dwords
  // end = OFF_TB + 7864320 = 11,788,704 floats ~= 47.2 MB (ws is 256 MiB)

  float* objIn   = ws + OFF_OBJIN;
  float* objOut  = ws + OFF_OBJOUT;
  float* metaAll = ws + OFF_METAALL;
  float* metaH   = ws + OFF_METAH;
  float* qsum    = ws + OFF_QSUM;
  float* esum    = ws + OFF_ESUM;
  float* Ut0     = ws + OFF_UT0;
  float* Ut1     = ws + OFF_UT1;
  float* Cm      = ws + OFF_CM;
  float* ol      = ws + OFF_OL;
  unsigned short* QTf    = (unsigned short*)(ws + OFF_QTF);
  unsigned short* AoptC  = (unsigned short*)(ws + OFF_AOPTC);
  unsigned short* AoptO  = (unsigned short*)(ws + OFF_AOPTO);
  unsigned short* awFrag = (unsigned short*)(ws + OFF_AWF);
  unsigned* TB           = (unsigned*)(ws + OFF_TB);

  Ptr16 ps;
  const int src_idx[16] = {0,1,2,3,4,5,6,8,9,10,11,12,13,14,15,16};
  for (int i=0;i<16;i++) ps.p[i] = d_in[src_idx[i]];

  k_prep<<<482, 256, 0, stream>>>(ps, flag, W, awFrag, gtc, gta, objIn, objOut, qsum);
  k_mid <<<224, 256, 0, stream>>>(ps, flag, meta_init, mw1, mb1, mw2, mb2,
                                  aw1, ab1, ops, args, objIn, objOut, awFrag,
                                  metaAll, metaH, QTf, qsum, AoptC, AoptO);
  k_T   <<<B_*LP*4*8, 64, 0, stream>>>(AoptC, AoptO, QTf, metaH, ops, TB);
  k_U   <<<B_*LP*2, 256, 0, stream>>>(TB, aw2, ab2, qsum, ops, Ut0, Ut1);
  k_rec <<<B_, 256, 0, stream>>>(Ut0, Ut1, metaAll, ops, att_init, Cm);
  k_out <<<B_*66, 256, 0, stream>>>(QTf, Cm, ol, esum);
  k_fin <<<(B_*NN + 255)/256, 256, 0, stream>>>(ol, esum, flag, d_out);
}